// Round 1
// baseline (3759.662 us; speedup 1.0000x reference)
//
#include <hip/hip_runtime.h>
#include <math.h>

#define B_ 16
#define L_ 512
#define D_ 768
#define HOPS_ 3

// ---------------------------------------------------------------------------
// sim GEMM: C[b][i][j] = sum_k A[b][i][k] * A[b][j][k]   (A * A^T per batch)
// A: [B][L][D], C: [B][L][L]
// ---------------------------------------------------------------------------
__global__ __launch_bounds__(256) void k_sim(const float* __restrict__ A,
                                             float* __restrict__ C) {
  int b = blockIdx.z;
  int i0 = blockIdx.y * 64, j0 = blockIdx.x * 64;
  const float* Ab = A + (size_t)b * L_ * D_;
  __shared__ float As[64][17];
  __shared__ float Bs[64][17];
  float acc[4][4] = {};
  int tx = threadIdx.x & 15, ty = threadIdx.x >> 4;
  for (int k0 = 0; k0 < D_; k0 += 16) {
#pragma unroll
    for (int t = 0; t < 4; ++t) {
      int idx = threadIdx.x + t * 256;
      int r = idx >> 4, c = idx & 15;
      As[r][c] = Ab[(size_t)(i0 + r) * D_ + k0 + c];
      Bs[r][c] = Ab[(size_t)(j0 + r) * D_ + k0 + c];
    }
    __syncthreads();
#pragma unroll
    for (int k = 0; k < 16; ++k) {
      float a[4], bb[4];
#pragma unroll
      for (int u = 0; u < 4; ++u) a[u] = As[ty * 4 + u][k];
#pragma unroll
      for (int v = 0; v < 4; ++v) bb[v] = Bs[tx * 4 + v][k];
#pragma unroll
      for (int u = 0; u < 4; ++u)
#pragma unroll
        for (int v = 0; v < 4; ++v) acc[u][v] += a[u] * bb[v];
    }
    __syncthreads();
  }
  float* Cb = C + (size_t)b * L_ * L_;
#pragma unroll
  for (int u = 0; u < 4; ++u)
#pragma unroll
    for (int v = 0; v < 4; ++v)
      Cb[(size_t)(i0 + ty * 4 + u) * L_ + j0 + tx * 4 + v] = acc[u][v];
}

// ---------------------------------------------------------------------------
// softmask (in-place on S): per row (b,i):
//   x = S/(r_i*r_j) (if rn), m = max_j x, y = exp(x-m)*mask_j,
//   att = y/(sum+1e-10)*mask_i
// ---------------------------------------------------------------------------
__global__ __launch_bounds__(256) void k_softmask(float* __restrict__ S,
                                                  const float* __restrict__ mask,
                                                  const float* __restrict__ rn) {
  int b = blockIdx.y, i = blockIdx.x;
  float* row = S + ((size_t)b * L_ + i) * L_;
  const float* mb = mask + (size_t)b * L_;
  int t = threadIdx.x;
  float v0 = row[t], v1 = row[t + 256];
  if (rn) {
    float inv_ri = 1.f / rn[(size_t)b * L_ + i];
    v0 *= inv_ri / rn[(size_t)b * L_ + t];
    v1 *= inv_ri / rn[(size_t)b * L_ + t + 256];
  }
  __shared__ float red[256];
  red[t] = fmaxf(v0, v1);
  __syncthreads();
  for (int s = 128; s > 0; s >>= 1) {
    if (t < s) red[t] = fmaxf(red[t], red[t + s]);
    __syncthreads();
  }
  float m = red[0];
  __syncthreads();
  float y0 = __expf(v0 - m) * mb[t];
  float y1 = __expf(v1 - m) * mb[t + 256];
  red[t] = y0 + y1;
  __syncthreads();
  for (int s = 128; s > 0; s >>= 1) {
    if (t < s) red[t] += red[t + s];
    __syncthreads();
  }
  float inv = 1.f / (red[0] + 1e-10f);
  float mi = mb[i];
  row[t] = y0 * inv * mi;
  row[t + 256] = y1 * inv * mi;
}

// ---------------------------------------------------------------------------
// attention apply: result[b][i][hoff..] = sum_j P[b][i][j] * V[b][j][d]
// P: [B][L][L], V: [B][L][D], result row stride 4*D
// ---------------------------------------------------------------------------
__global__ __launch_bounds__(256) void k_att(const float* __restrict__ P,
                                             const float* __restrict__ V,
                                             float* __restrict__ Cout, int hoff) {
  int b = blockIdx.z;
  int i0 = blockIdx.y * 64, d0 = blockIdx.x * 64;
  const float* Pb = P + (size_t)b * L_ * L_;
  const float* Vb = V + (size_t)b * L_ * D_;
  __shared__ float As[64][17];
  __shared__ float Bs[16][64];
  float acc[4][4] = {};
  int tx = threadIdx.x & 15, ty = threadIdx.x >> 4;
  for (int k0 = 0; k0 < L_; k0 += 16) {
#pragma unroll
    for (int t = 0; t < 4; ++t) {
      int idx = threadIdx.x + t * 256;
      int r = idx >> 4, c = idx & 15;
      As[r][c] = Pb[(size_t)(i0 + r) * L_ + k0 + c];
      int rr = idx >> 6, cc = idx & 63;
      Bs[rr][cc] = Vb[(size_t)(k0 + rr) * D_ + d0 + cc];
    }
    __syncthreads();
#pragma unroll
    for (int k = 0; k < 16; ++k) {
      float a[4], bb[4];
#pragma unroll
      for (int u = 0; u < 4; ++u) a[u] = As[ty * 4 + u][k];
#pragma unroll
      for (int v = 0; v < 4; ++v) bb[v] = Bs[k][tx * 4 + v];
#pragma unroll
      for (int u = 0; u < 4; ++u)
#pragma unroll
        for (int v = 0; v < 4; ++v) acc[u][v] += a[u] * bb[v];
    }
    __syncthreads();
  }
#pragma unroll
  for (int u = 0; u < 4; ++u) {
    int i = i0 + ty * 4 + u;
    float* Crow = Cout + ((size_t)(b * L_ + i) * 4) * D_ + hoff;
#pragma unroll
    for (int v = 0; v < 4; ++v) Crow[d0 + tx * 4 + v] = acc[u][v];
  }
}

// ---------------------------------------------------------------------------
// conv1d (k=3, pad 1) as im2col GEMM + bias + relu
// X: [B][L][D], Wt: [3*D][D] (= wT[k][i][o]), Y: [B][L][D]
// ---------------------------------------------------------------------------
__global__ __launch_bounds__(256) void k_conv(const float* __restrict__ X,
                                              const float* __restrict__ Wt,
                                              const float* __restrict__ bias,
                                              float* __restrict__ Y) {
  int b = blockIdx.z;
  int l0 = blockIdx.y * 64, o0 = blockIdx.x * 64;
  const float* Xb = X + (size_t)b * L_ * D_;
  __shared__ float As[64][17];
  __shared__ float Bs[16][64];
  float acc[4][4] = {};
  int tx = threadIdx.x & 15, ty = threadIdx.x >> 4;
  for (int k0 = 0; k0 < 3 * D_; k0 += 16) {
    int kk = k0 / D_;          // kernel tap (K-tiles never cross taps: 768%16==0)
    int ic0 = k0 - kk * D_;    // input channel base
#pragma unroll
    for (int t = 0; t < 4; ++t) {
      int idx = threadIdx.x + t * 256;
      int r = idx >> 4, c = idx & 15;
      int lrow = l0 + r + kk - 1;
      As[r][c] = (lrow >= 0 && lrow < L_) ? Xb[(size_t)lrow * D_ + ic0 + c] : 0.f;
      int rr = idx >> 6, cc = idx & 63;
      Bs[rr][cc] = Wt[(size_t)(k0 + rr) * D_ + o0 + cc];
    }
    __syncthreads();
#pragma unroll
    for (int k = 0; k < 16; ++k) {
      float a[4], bb[4];
#pragma unroll
      for (int u = 0; u < 4; ++u) a[u] = As[ty * 4 + u][k];
#pragma unroll
      for (int v = 0; v < 4; ++v) bb[v] = Bs[k][tx * 4 + v];
#pragma unroll
      for (int u = 0; u < 4; ++u)
#pragma unroll
        for (int v = 0; v < 4; ++v) acc[u][v] += a[u] * bb[v];
    }
    __syncthreads();
  }
#pragma unroll
  for (int u = 0; u < 4; ++u) {
    int l = l0 + ty * 4 + u;
#pragma unroll
    for (int v = 0; v < 4; ++v) {
      int o = o0 + tx * 4 + v;
      float val = acc[u][v] + bias[o];
      Y[((size_t)b * L_ + l) * D_ + o] = fmaxf(val, 0.f);
    }
  }
}

// ---------------------------------------------------------------------------
// row L2 norms (clamped at 1e-12)
// ---------------------------------------------------------------------------
__global__ __launch_bounds__(256) void k_rownorm(const float* __restrict__ X,
                                                 float* __restrict__ rn) {
  int b = blockIdx.y, l = blockIdx.x;
  const float* row = X + ((size_t)b * L_ + l) * D_;
  int t = threadIdx.x;
  float s = 0.f;
  for (int d = t; d < D_; d += 256) s += row[d] * row[d];
  __shared__ float red[256];
  red[t] = s;
  __syncthreads();
  for (int st = 128; st > 0; st >>= 1) {
    if (t < st) red[t] += red[t + st];
    __syncthreads();
  }
  if (t == 0) rn[(size_t)b * L_ + l] = fmaxf(sqrtf(red[0]), 1e-12f);
}

// ---------------------------------------------------------------------------
// conv weight transpose: wT[h][k][i][o] = w[h][o][i][k]
// ---------------------------------------------------------------------------
__global__ void k_wtrans(const float* __restrict__ w, float* __restrict__ wT) {
  size_t idx = (size_t)blockIdx.x * 256 + threadIdx.x;
  const size_t total = (size_t)HOPS_ * 3 * D_ * D_;
  if (idx >= total) return;
  int o = (int)(idx % D_);
  size_t r = idx / D_;
  int i = (int)(r % D_);
  r /= D_;
  int k = (int)(r % 3);
  int h = (int)(r / 3);
  wT[idx] = w[(((size_t)h * D_ + o) * D_ + i) * 3 + k];
}

// ---------------------------------------------------------------------------
// pooling scores: ps[b][l][h] = w2 . tanh(W1^T R[b][l][h] + b1) + b2
// One block per (b,l); W1 streamed exactly once per block.
// ---------------------------------------------------------------------------
__global__ __launch_bounds__(256) void k_pool(const float* __restrict__ R,
                                              const float* __restrict__ W1,
                                              const float* __restrict__ b1,
                                              const float* __restrict__ w2,
                                              const float* __restrict__ b2,
                                              float* __restrict__ ps) {
  int b = blockIdx.y, l = blockIdx.x;
  const float* Rrow = R + ((size_t)b * L_ + l) * 4 * D_;
  __shared__ float res[4][D_];
  int t = threadIdx.x;
  for (int idx = t; idx < 4 * D_; idx += 256) res[idx / D_][idx % D_] = Rrow[idx];
  __syncthreads();
  float acc[3][4];
#pragma unroll
  for (int es = 0; es < 3; ++es) {
    float bv = b1[t + es * 256];
#pragma unroll
    for (int h = 0; h < 4; ++h) acc[es][h] = bv;
  }
  for (int d = 0; d < D_; ++d) {
    float r0 = res[0][d], r1 = res[1][d], r2 = res[2][d], r3 = res[3][d];
#pragma unroll
    for (int es = 0; es < 3; ++es) {
      float w = W1[(size_t)d * D_ + t + es * 256];
      acc[es][0] += r0 * w;
      acc[es][1] += r1 * w;
      acc[es][2] += r2 * w;
      acc[es][3] += r3 * w;
    }
  }
  float part[4] = {0.f, 0.f, 0.f, 0.f};
#pragma unroll
  for (int es = 0; es < 3; ++es) {
    float wv = w2[t + es * 256];
#pragma unroll
    for (int h = 0; h < 4; ++h) part[h] += tanhf(acc[es][h]) * wv;
  }
  __shared__ float red[4][256];
#pragma unroll
  for (int h = 0; h < 4; ++h) red[h][t] = part[h];
  __syncthreads();
  for (int s = 128; s > 0; s >>= 1) {
    if (t < s) {
#pragma unroll
      for (int h = 0; h < 4; ++h) red[h][t] += red[h][t + s];
    }
    __syncthreads();
  }
  if (t < 4) ps[((size_t)b * L_ + l) * 4 + t] = red[t][0] + b2[0];
}

// ---------------------------------------------------------------------------
// weighted combine: out[b][l][d] = sum_h softmax(ps)[h] * R[b][l][h][d]
// ---------------------------------------------------------------------------
__global__ __launch_bounds__(256) void k_weighted(const float* __restrict__ R,
                                                  const float* __restrict__ ps,
                                                  float* __restrict__ out) {
  int b = blockIdx.y, l = blockIdx.x;
  const float* p = ps + ((size_t)b * L_ + l) * 4;
  float s0 = p[0], s1 = p[1], s2 = p[2], s3 = p[3];
  float m = fmaxf(fmaxf(s0, s1), fmaxf(s2, s3));
  float e0 = __expf(s0 - m), e1 = __expf(s1 - m), e2 = __expf(s2 - m),
        e3 = __expf(s3 - m);
  float inv = 1.f / (e0 + e1 + e2 + e3);
  e0 *= inv; e1 *= inv; e2 *= inv; e3 *= inv;
  const float* Rrow = R + ((size_t)b * L_ + l) * 4 * D_;
  float* orow = out + ((size_t)b * L_ + l) * D_;
  for (int d = threadIdx.x; d < D_; d += 256) {
    orow[d] = e0 * Rrow[d] + e1 * Rrow[D_ + d] + e2 * Rrow[2 * D_ + d] +
              e3 * Rrow[3 * D_ + d];
  }
}

extern "C" void kernel_launch(void* const* d_in, const int* in_sizes, int n_in,
                              void* d_out, int out_size, void* d_ws, size_t ws_size,
                              hipStream_t stream) {
  const float* inputs  = (const float*)d_in[0];
  const float* mask    = (const float*)d_in[1];
  const float* conv_w  = (const float*)d_in[2];
  const float* conv_b  = (const float*)d_in[3];
  const float* pool_w1 = (const float*)d_in[4];
  const float* pool_b1 = (const float*)d_in[5];
  const float* pool_w2 = (const float*)d_in[6];
  const float* pool_b2 = (const float*)d_in[7];
  float* out = (float*)d_out;
  float* ws = (float*)d_ws;

  const size_t BLD = (size_t)B_ * L_ * D_;
  const size_t BLL = (size_t)B_ * L_ * L_;

  float* S      = ws;
  float* convA  = S + BLL;
  float* convB  = convA + BLD;
  float* result = convB + BLD;
  float* rn     = result + 4 * BLD;
  float* ps     = rn + (size_t)B_ * L_;
  float* wT     = ps + 4 * (size_t)B_ * L_;

  const size_t wtot = (size_t)HOPS_ * 3 * D_ * D_;
  k_wtrans<<<dim3((unsigned)((wtot + 255) / 256)), 256, 0, stream>>>(conv_w, wT);

  dim3 gs(L_ / 64, L_ / 64, B_);  // (8,8,16)   sim
  dim3 ga(D_ / 64, L_ / 64, B_);  // (12,8,16)  att apply / conv
  dim3 gr(L_, B_);                // per-row kernels

  // hop 0: raw similarity on inputs
  k_sim<<<gs, 256, 0, stream>>>(inputs, S);
  k_softmask<<<gr, 256, 0, stream>>>(S, mask, nullptr);
  k_att<<<ga, 256, 0, stream>>>(S, inputs, result, 0);

  const float* cur = inputs;
  float* bufs[2] = {convA, convB};
  for (int h = 0; h < HOPS_; ++h) {
    float* cv = bufs[h & 1];  // h0->A, h1->B, h2->A  => final cur == convA
    k_conv<<<ga, 256, 0, stream>>>(cur, wT + (size_t)h * 3 * D_ * D_,
                                   conv_b + (size_t)h * D_, cv);
    k_rownorm<<<gr, 256, 0, stream>>>(cv, rn);
    k_sim<<<gs, 256, 0, stream>>>(cv, S);
    k_softmask<<<gr, 256, 0, stream>>>(S, mask, rn);
    k_att<<<ga, 256, 0, stream>>>(S, cv, result, (h + 1) * D_);
    cur = cv;
  }

  k_pool<<<gr, 256, 0, stream>>>(result, pool_w1, pool_b1, pool_w2, pool_b2, ps);
  k_weighted<<<gr, 256, 0, stream>>>(result, ps, out + BLD);
  hipMemcpyAsync(out, cur, BLD * sizeof(float), hipMemcpyDeviceToDevice, stream);
}

// Round 2
// 881.603 us; speedup vs baseline: 4.2646x; 4.2646x over previous
//
#include <hip/hip_runtime.h>
#include <math.h>

#define B_ 16
#define L_ 512
#define D_ 768
#define HOPS_ 3

typedef __attribute__((ext_vector_type(8))) short s16x8;
typedef __attribute__((ext_vector_type(4))) short s16x4;
typedef __attribute__((ext_vector_type(4))) float f32x4;

#define LDSK 40  // 32 k + 8 pad shorts (80B rows: ~2-way bank pattern, free)

__device__ __forceinline__ short f2bf(float f) {
  unsigned u = __float_as_uint(f);
  unsigned r = (u + 0x7fffu + ((u >> 16) & 1u)) >> 16;
  return (short)r;
}
__device__ __forceinline__ float bf2f(short s) {
  unsigned u = ((unsigned)(unsigned short)s) << 16;
  return __uint_as_float(u);
}

// stage 16 f32 -> 16 bf16 into LDS (dst 16B-aligned, src 16B-aligned)
__device__ __forceinline__ void cvt_store16(short* dst, const float* src) {
  float4 q0 = ((const float4*)src)[0];
  float4 q1 = ((const float4*)src)[1];
  float4 q2 = ((const float4*)src)[2];
  float4 q3 = ((const float4*)src)[3];
  s16x8 a, b;
  a[0] = f2bf(q0.x); a[1] = f2bf(q0.y); a[2] = f2bf(q0.z); a[3] = f2bf(q0.w);
  a[4] = f2bf(q1.x); a[5] = f2bf(q1.y); a[6] = f2bf(q1.z); a[7] = f2bf(q1.w);
  b[0] = f2bf(q2.x); b[1] = f2bf(q2.y); b[2] = f2bf(q2.z); b[3] = f2bf(q2.w);
  b[4] = f2bf(q3.x); b[5] = f2bf(q3.y); b[6] = f2bf(q3.z); b[7] = f2bf(q3.w);
  ((s16x8*)dst)[0] = a;
  ((s16x8*)dst)[1] = b;
}

// stage 16 bf16 -> LDS (straight copy)
__device__ __forceinline__ void copy16bf(short* dst, const short* src) {
  ((s16x8*)dst)[0] = ((const s16x8*)src)[0];
  ((s16x8*)dst)[1] = ((const s16x8*)src)[1];
}

__device__ __forceinline__ void zero16(short* dst) {
  s16x8 z = {0, 0, 0, 0, 0, 0, 0, 0};
  ((s16x8*)dst)[0] = z;
  ((s16x8*)dst)[1] = z;
}

// 128x128 tile, 4 waves (2x2 of 64x64), K-step 32: 16 MFMA per wave
__device__ __forceinline__ void mfma_step(const short (*As)[LDSK], const short (*Bs)[LDSK],
                                          f32x4 acc[4][4], int wr, int wc, int lq, int lr) {
  int ko = 8 * lq;
  s16x8 av[4], bv[4];
#pragma unroll
  for (int m = 0; m < 4; ++m) av[m] = *(const s16x8*)&As[wr * 64 + m * 16 + lr][ko];
#pragma unroll
  for (int n = 0; n < 4; ++n) bv[n] = *(const s16x8*)&Bs[wc * 64 + n * 16 + lr][ko];
#pragma unroll
  for (int m = 0; m < 4; ++m)
#pragma unroll
    for (int n = 0; n < 4; ++n)
      acc[m][n] = __builtin_amdgcn_mfma_f32_16x16x32_bf16(av[m], bv[n], acc[m][n], 0, 0, 0);
}

// ---------------------------------------------------------------------------
// sim: S[b][i][j] = sum_k A[b][i][k]*A[b][j][k]
// SPLIT=1: A = Xs [B][L][1536] bf16 (hi|lo), virtual K=2304 with A-seg {hi,lo,hi},
//          B-seg {hi,hi,lo}  => (hi+lo)x(hi+lo) minus lo*lo (~2^-18) exact-ish.
// SPLIT=0: A = f32 [B][L][768], convert in staging.
// ---------------------------------------------------------------------------
template <int SPLIT>
__global__ __launch_bounds__(256) void k_sim_mfma(const void* __restrict__ Asrc,
                                                  float* __restrict__ Sout) {
  int b = blockIdx.z;
  int i0 = blockIdx.y * 128, j0 = blockIdx.x * 128;
  int t = threadIdx.x, lane = t & 63, wid = t >> 6;
  int wr = wid >> 1, wc = wid & 1, lq = lane >> 4, lr = lane & 15;
  __shared__ __align__(16) short As[128][LDSK];
  __shared__ __align__(16) short Bs[128][LDSK];
  f32x4 acc[4][4];
#pragma unroll
  for (int m = 0; m < 4; ++m)
#pragma unroll
    for (int n = 0; n < 4; ++n) acc[m][n] = (f32x4){0.f, 0.f, 0.f, 0.f};

  const int K = SPLIT ? 2304 : 768;
  int r = t >> 1, kb = (t & 1) * 16;
  for (int k0 = 0; k0 < K; k0 += 32) {
    if (SPLIT) {
      const short* X = (const short*)Asrc + (size_t)b * L_ * 1536;
      int seg = k0 / 768, kl = k0 - seg * 768 + kb;
      int ak = kl + (seg == 1 ? 768 : 0);
      int bk = kl + (seg == 2 ? 768 : 0);
      copy16bf(&As[r][kb], X + (size_t)(i0 + r) * 1536 + ak);
      copy16bf(&Bs[r][kb], X + (size_t)(j0 + r) * 1536 + bk);
    } else {
      const float* X = (const float*)Asrc + (size_t)b * L_ * D_;
      cvt_store16(&As[r][kb], X + (size_t)(i0 + r) * D_ + k0 + kb);
      cvt_store16(&Bs[r][kb], X + (size_t)(j0 + r) * D_ + k0 + kb);
    }
    __syncthreads();
    mfma_step(As, Bs, acc, wr, wc, lq, lr);
    __syncthreads();
  }
  float* Cb = Sout + (size_t)b * L_ * L_;
#pragma unroll
  for (int m = 0; m < 4; ++m)
#pragma unroll
    for (int n = 0; n < 4; ++n)
#pragma unroll
      for (int rr = 0; rr < 4; ++rr)
        Cb[(size_t)(i0 + wr * 64 + m * 16 + 4 * lq + rr) * L_ +
           (j0 + wc * 64 + n * 16 + lr)] = acc[m][n][rr];
}

// ---------------------------------------------------------------------------
// att apply: R[b][i][hop][d] = sum_j P[b][i][j] * V[b][j][d]  (R stored bf16)
// P bf16 [B][L][L]; V bf16 (VBF16=1) or f32, row stride ldv; transposed B-stage.
// ---------------------------------------------------------------------------
template <int VBF16>
__global__ __launch_bounds__(256) void k_att_mfma(const short* __restrict__ P,
                                                  const void* __restrict__ V, int ldv,
                                                  short* __restrict__ Rb, int hop) {
  int b = blockIdx.z;
  int i0 = blockIdx.y * 128, d0 = blockIdx.x * 128;
  int t = threadIdx.x, lane = t & 63, wid = t >> 6;
  int wr = wid >> 1, wc = wid & 1, lq = lane >> 4, lr = lane & 15;
  __shared__ __align__(16) short As[128][LDSK];
  __shared__ __align__(16) short Bs[128][LDSK];
  f32x4 acc[4][4];
#pragma unroll
  for (int m = 0; m < 4; ++m)
#pragma unroll
    for (int n = 0; n < 4; ++n) acc[m][n] = (f32x4){0.f, 0.f, 0.f, 0.f};

  const short* Pb = P + (size_t)b * L_ * L_;
  const short* Vb = (const short*)V + (size_t)b * L_ * ldv;
  const float* Vf = (const float*)V + (size_t)b * L_ * ldv;
  int r = t >> 1, kb = (t & 1) * 16;
  for (int k0 = 0; k0 < L_; k0 += 32) {
    copy16bf(&As[r][kb], Pb + (size_t)(i0 + r) * L_ + k0 + kb);
    // transposed V staging: Bs[d][k] = bf16(V[k0+k][d0+d]); d = r, 16 k's
#pragma unroll
    for (int g = 0; g < 4; ++g) {
      s16x4 q;
#pragma unroll
      for (int kk = 0; kk < 4; ++kk) {
        int k = k0 + kb + 4 * g + kk;
        q[kk] = VBF16 ? Vb[(size_t)k * ldv + d0 + r] : f2bf(Vf[(size_t)k * ldv + d0 + r]);
      }
      *(s16x4*)&Bs[r][kb + 4 * g] = q;
    }
    __syncthreads();
    mfma_step(As, Bs, acc, wr, wc, lq, lr);
    __syncthreads();
  }
#pragma unroll
  for (int m = 0; m < 4; ++m)
#pragma unroll
    for (int n = 0; n < 4; ++n)
#pragma unroll
      for (int rr = 0; rr < 4; ++rr) {
        int i = i0 + wr * 64 + m * 16 + 4 * lq + rr;
        int d = d0 + wc * 64 + n * 16 + lr;
        Rb[((size_t)(b * L_ + i) * 4 + hop) * D_ + d] = f2bf(acc[m][n][rr]);
      }
}

// ---------------------------------------------------------------------------
// conv1d(k=3,pad1) im2col GEMM + bias + relu -> f32 Y
// X bf16 (XBF16=1, row stride ldx) or f32; Wt2 bf16 [o][2304] (= w[o][i][kk] tap-major)
// ---------------------------------------------------------------------------
template <int XBF16>
__global__ __launch_bounds__(256) void k_conv_mfma(const void* __restrict__ X, int ldx,
                                                   const short* __restrict__ Wt2,
                                                   const float* __restrict__ bias,
                                                   float* __restrict__ Y) {
  int b = blockIdx.z;
  int l0 = blockIdx.y * 128, o0 = blockIdx.x * 128;
  int t = threadIdx.x, lane = t & 63, wid = t >> 6;
  int wr = wid >> 1, wc = wid & 1, lq = lane >> 4, lr = lane & 15;
  __shared__ __align__(16) short As[128][LDSK];
  __shared__ __align__(16) short Bs[128][LDSK];
  f32x4 acc[4][4];
#pragma unroll
  for (int m = 0; m < 4; ++m)
#pragma unroll
    for (int n = 0; n < 4; ++n) acc[m][n] = (f32x4){0.f, 0.f, 0.f, 0.f};

  const short* Xb = (const short*)X + (size_t)b * L_ * ldx;
  const float* Xf = (const float*)X + (size_t)b * L_ * ldx;
  int r = t >> 1, kb = (t & 1) * 16;
  for (int k0 = 0; k0 < 3 * D_; k0 += 32) {
    int tap = k0 / D_;
    int ic = k0 - tap * D_ + kb;
    int l = l0 + r + tap - 1;
    if (l >= 0 && l < L_) {
      if (XBF16) copy16bf(&As[r][kb], Xb + (size_t)l * ldx + ic);
      else       cvt_store16(&As[r][kb], Xf + (size_t)l * ldx + ic);
    } else {
      zero16(&As[r][kb]);
    }
    copy16bf(&Bs[r][kb], Wt2 + (size_t)(o0 + r) * (3 * D_) + k0 + kb);
    __syncthreads();
    mfma_step(As, Bs, acc, wr, wc, lq, lr);
    __syncthreads();
  }
  float bv[4];
#pragma unroll
  for (int n = 0; n < 4; ++n) bv[n] = bias[o0 + wc * 64 + n * 16 + lr];
#pragma unroll
  for (int m = 0; m < 4; ++m)
#pragma unroll
    for (int n = 0; n < 4; ++n)
#pragma unroll
      for (int rr = 0; rr < 4; ++rr) {
        int l = l0 + wr * 64 + m * 16 + 4 * lq + rr;
        int o = o0 + wc * 64 + n * 16 + lr;
        Y[((size_t)b * L_ + l) * D_ + o] = fmaxf(acc[m][n][rr] + bv[n], 0.f);
      }
}

// ---------------------------------------------------------------------------
// pool GEMM: hidden[r][e] = Rb[r][:]*W1t[e][:]; ps[r] += sum_e tanh(h+b1[e])*w2[e]
// Rb bf16 [32768][768]; W1t bf16 [768][768] (W1 transposed). ps pre-zeroed.
// ---------------------------------------------------------------------------
__global__ __launch_bounds__(256) void k_pool_mfma(const short* __restrict__ Rb,
                                                   const short* __restrict__ W1t,
                                                   const float* __restrict__ b1,
                                                   const float* __restrict__ w2,
                                                   float* __restrict__ ps) {
  int r0 = blockIdx.y * 128, e0 = blockIdx.x * 128;
  int t = threadIdx.x, lane = t & 63, wid = t >> 6;
  int wr = wid >> 1, wc = wid & 1, lq = lane >> 4, lr = lane & 15;
  __shared__ __align__(16) short As[128][LDSK];
  __shared__ __align__(16) short Bs[128][LDSK];
  f32x4 acc[4][4];
#pragma unroll
  for (int m = 0; m < 4; ++m)
#pragma unroll
    for (int n = 0; n < 4; ++n) acc[m][n] = (f32x4){0.f, 0.f, 0.f, 0.f};

  int r = t >> 1, kb = (t & 1) * 16;
  for (int k0 = 0; k0 < D_; k0 += 32) {
    copy16bf(&As[r][kb], Rb + (size_t)(r0 + r) * D_ + k0 + kb);
    copy16bf(&Bs[r][kb], W1t + (size_t)(e0 + r) * D_ + k0 + kb);
    __syncthreads();
    mfma_step(As, Bs, acc, wr, wc, lq, lr);
    __syncthreads();
  }
  float b1v[4], w2v[4];
#pragma unroll
  for (int n = 0; n < 4; ++n) {
    int e = e0 + wc * 64 + n * 16 + lr;
    b1v[n] = b1[e];
    w2v[n] = w2[e];
  }
#pragma unroll
  for (int m = 0; m < 4; ++m)
#pragma unroll
    for (int rr = 0; rr < 4; ++rr) {
      float p = 0.f;
#pragma unroll
      for (int n = 0; n < 4; ++n) p += tanhf(acc[m][n][rr] + b1v[n]) * w2v[n];
      p += __shfl_xor(p, 1);
      p += __shfl_xor(p, 2);
      p += __shfl_xor(p, 4);
      p += __shfl_xor(p, 8);
      if (lr == 0) atomicAdd(&ps[r0 + wr * 64 + m * 16 + 4 * lq + rr], p);
    }
}

// ---------------------------------------------------------------------------
// softmask: read S f32, write P bf16. rn==nullptr => no cosine normalization.
// ---------------------------------------------------------------------------
__global__ __launch_bounds__(256) void k_softmask2(const float* __restrict__ S,
                                                   const float* __restrict__ mask,
                                                   const float* __restrict__ rn,
                                                   short* __restrict__ P) {
  int b = blockIdx.y, i = blockIdx.x;
  const float* row = S + ((size_t)b * L_ + i) * L_;
  short* prow = P + ((size_t)b * L_ + i) * L_;
  const float* mb = mask + (size_t)b * L_;
  int t = threadIdx.x;
  float v0 = row[t], v1 = row[t + 256];
  if (rn) {
    float inv_ri = 1.f / rn[(size_t)b * L_ + i];
    v0 *= inv_ri / rn[(size_t)b * L_ + t];
    v1 *= inv_ri / rn[(size_t)b * L_ + t + 256];
  }
  __shared__ float red[256];
  red[t] = fmaxf(v0, v1);
  __syncthreads();
  for (int s = 128; s > 0; s >>= 1) {
    if (t < s) red[t] = fmaxf(red[t], red[t + s]);
    __syncthreads();
  }
  float m = red[0];
  __syncthreads();
  float y0 = __expf(v0 - m) * mb[t];
  float y1 = __expf(v1 - m) * mb[t + 256];
  red[t] = y0 + y1;
  __syncthreads();
  for (int s = 128; s > 0; s >>= 1) {
    if (t < s) red[t] += red[t + s];
    __syncthreads();
  }
  float inv = 1.f / (red[0] + 1e-10f);
  float mi = mb[i];
  prow[t] = f2bf(y0 * inv * mi);
  prow[t + 256] = f2bf(y1 * inv * mi);
}

__global__ __launch_bounds__(256) void k_rownorm(const float* __restrict__ X,
                                                 float* __restrict__ rn) {
  int b = blockIdx.y, l = blockIdx.x;
  const float* row = X + ((size_t)b * L_ + l) * D_;
  int t = threadIdx.x;
  float s = 0.f;
  for (int d = t; d < D_; d += 256) s += row[d] * row[d];
  __shared__ float red[256];
  red[t] = s;
  __syncthreads();
  for (int st = 128; st > 0; st >>= 1) {
    if (t < st) red[t] += red[t + st];
    __syncthreads();
  }
  if (t == 0) rn[(size_t)b * L_ + l] = fmaxf(sqrtf(red[0]), 1e-12f);
}

// inputs f32 -> Xs bf16 [B*L][1536] = [hi | lo]
__global__ void k_prep(const float* __restrict__ in, short* __restrict__ Xs) {
  size_t idx = (size_t)blockIdx.x * 256 + threadIdx.x;
  if (idx >= (size_t)B_ * L_ * D_) return;
  size_t bl = idx / D_;
  int d = (int)(idx % D_);
  float x = in[idx];
  short hi = f2bf(x);
  short lo = f2bf(x - bf2f(hi));
  Xs[bl * 1536 + d] = hi;
  Xs[bl * 1536 + 768 + d] = lo;
}

// conv_w [h][o][i][kk] -> Wt2 bf16 [h][o][kk*768+i]
__global__ void k_wtrans2(const float* __restrict__ w, short* __restrict__ Wt2) {
  size_t idx = (size_t)blockIdx.x * 256 + threadIdx.x;
  const size_t total = (size_t)HOPS_ * D_ * 3 * D_;
  if (idx >= total) return;
  int i = (int)(idx % D_);
  size_t tmp = idx / D_;
  int kk = (int)(tmp % 3);
  tmp /= 3;
  int o = (int)(tmp % D_);
  int h = (int)(tmp / D_);
  Wt2[idx] = f2bf(w[(((size_t)h * D_ + o) * D_ + i) * 3 + kk]);
}

// W1 [d][e] -> W1t bf16 [e][d]
__global__ void k_w1t(const float* __restrict__ W1, short* __restrict__ W1t) {
  size_t idx = (size_t)blockIdx.x * 256 + threadIdx.x;
  if (idx >= (size_t)D_ * D_) return;
  int e = (int)(idx / D_), d = (int)(idx % D_);
  W1t[idx] = f2bf(W1[(size_t)d * D_ + e]);
}

// out[b][l][d] = sum_h softmax(ps[bl*4+h])_h * Rb[bl][h][d]
__global__ __launch_bounds__(256) void k_weighted2(const short* __restrict__ Rb,
                                                   const float* __restrict__ ps,
                                                   float* __restrict__ out) {
  int b = blockIdx.y, l = blockIdx.x;
  size_t bl = (size_t)b * L_ + l;
  const float* p = ps + bl * 4;
  float s0 = p[0], s1 = p[1], s2 = p[2], s3 = p[3];
  float m = fmaxf(fmaxf(s0, s1), fmaxf(s2, s3));
  float e0 = __expf(s0 - m), e1 = __expf(s1 - m), e2 = __expf(s2 - m),
        e3 = __expf(s3 - m);
  float inv = 1.f / (e0 + e1 + e2 + e3);
  e0 *= inv; e1 *= inv; e2 *= inv; e3 *= inv;
  const short* Rrow = Rb + bl * 4 * D_;
  float* orow = out + bl * D_;
  for (int d = threadIdx.x; d < D_; d += 256) {
    orow[d] = e0 * bf2f(Rrow[d]) + e1 * bf2f(Rrow[D_ + d]) +
              e2 * bf2f(Rrow[2 * D_ + d]) + e3 * bf2f(Rrow[3 * D_ + d]);
  }
}

extern "C" void kernel_launch(void* const* d_in, const int* in_sizes, int n_in,
                              void* d_out, int out_size, void* d_ws, size_t ws_size,
                              hipStream_t stream) {
  const float* inputs  = (const float*)d_in[0];
  const float* mask    = (const float*)d_in[1];
  const float* conv_w  = (const float*)d_in[2];
  const float* conv_b  = (const float*)d_in[3];
  const float* pool_w1 = (const float*)d_in[4];
  const float* pool_b1 = (const float*)d_in[5];
  const float* pool_w2 = (const float*)d_in[6];
  // pool_b2 (d_in[7]) unused: softmax is shift-invariant.
  float* out = (float*)d_out;

  const size_t BLD = (size_t)B_ * L_ * D_;   // 6,291,456
  const size_t BLL = (size_t)B_ * L_ * L_;   // 4,194,304

  char* w = (char*)d_ws;
  short* Xs   = (short*)w; w += 2 * BLD * 2;        // 25.2 MB  [hi|lo]
  short* Wt2  = (short*)w; w += (size_t)HOPS_ * 3 * D_ * D_ * 2;  // 10.6 MB
  short* W1t  = (short*)w; w += (size_t)D_ * D_ * 2;              // 1.2 MB
  float* S    = (float*)w; w += BLL * 4;            // 16.8 MB
  short* Pb   = (short*)w; w += BLL * 2;            // 8.4 MB
  float* convA = (float*)w; w += BLD * 4;           // 25.2 MB
  float* convB = (float*)w; w += BLD * 4;           // 25.2 MB
  short* Rb   = (short*)w; w += 4 * BLD * 2;        // 50.3 MB
  float* rn   = (float*)w; w += (size_t)B_ * L_ * 4;
  float* ps   = (float*)w; w += (size_t)B_ * L_ * 4 * 4;

  // --- prep passes ---
  k_prep<<<dim3((unsigned)((BLD + 255) / 256)), 256, 0, stream>>>(inputs, Xs);
  {
    size_t tot = (size_t)HOPS_ * D_ * 3 * D_;
    k_wtrans2<<<dim3((unsigned)((tot + 255) / 256)), 256, 0, stream>>>(conv_w, Wt2);
  }
  k_w1t<<<dim3((unsigned)(((size_t)D_ * D_ + 255) / 256)), 256, 0, stream>>>(pool_w1, W1t);

  dim3 gsim(L_ / 128, L_ / 128, B_);   // (4,4,16)
  dim3 gatt(D_ / 128, L_ / 128, B_);   // (6,4,16)
  dim3 gpool(D_ / 128, (4 * B_ * L_) / 128);  // (6,256)
  dim3 grow(L_, B_);

  // --- hop 0: split-bf16 exact similarity on raw inputs ---
  k_sim_mfma<1><<<gsim, 256, 0, stream>>>(Xs, S);
  k_softmask2<<<grow, 256, 0, stream>>>(S, mask, nullptr, Pb);
  k_att_mfma<1><<<gatt, 256, 0, stream>>>(Pb, Xs, 1536, Rb, 0);

  // --- hops 1..3 ---
  const void* cur = Xs;  // bf16 hi, stride 1536
  int curbf = 1, ldc = 1536;
  float* bufs[2] = {convA, convB};
  for (int h = 0; h < HOPS_; ++h) {
    float* cv = bufs[h & 1];  // h0->A, h1->B, h2->A => final cur == convA
    const short* Wh = Wt2 + (size_t)h * 3 * D_ * D_;
    const float* bh = conv_b + (size_t)h * D_;
    if (curbf) k_conv_mfma<1><<<gatt, 256, 0, stream>>>(cur, ldc, Wh, bh, cv);
    else       k_conv_mfma<0><<<gatt, 256, 0, stream>>>(cur, ldc, Wh, bh, cv);
    k_rownorm<<<grow, 256, 0, stream>>>(cv, rn);
    k_sim_mfma<0><<<gsim, 256, 0, stream>>>(cv, S);
    k_softmask2<<<grow, 256, 0, stream>>>(S, mask, rn, Pb);
    k_att_mfma<0><<<gatt, 256, 0, stream>>>(Pb, cv, D_, Rb, h + 1);
    cur = cv; curbf = 0; ldc = D_;
  }

  // --- pooling ---
  hipMemsetAsync(ps, 0, (size_t)B_ * L_ * 4 * sizeof(float), stream);
  k_pool_mfma<<<gpool, 256, 0, stream>>>(Rb, W1t, pool_b1, pool_w2, ps);
  k_weighted2<<<grow, 256, 0, stream>>>(Rb, ps, out + BLD);

  // output 0: final conv activation (f32, convA)
  hipMemcpyAsync(out, convA, BLD * sizeof(float), hipMemcpyDeviceToDevice, stream);
}

// Round 3
// 643.982 us; speedup vs baseline: 5.8382x; 1.3690x over previous
//
#include <hip/hip_runtime.h>
#include <math.h>

#define B_ 16
#define L_ 512
#define D_ 768
#define HOPS_ 3
#define LK 32  // K-step in shorts; rows are 64B, swizzled 16B slots

typedef __attribute__((ext_vector_type(8))) short s16x8;
typedef __attribute__((ext_vector_type(4))) float f32x4;

__device__ __forceinline__ short f2bf(float f) {
  unsigned u = __float_as_uint(f);
  unsigned r = (u + 0x7fffu + ((u >> 16) & 1u)) >> 16;
  return (short)r;
}
__device__ __forceinline__ float bf2f(short s) {
  unsigned u = ((unsigned)(unsigned short)s) << 16;
  return __uint_as_float(u);
}

// swizzled 16B-slot pointer: phys_slot = slot ^ ((row>>1)&3).
// Reads (16 lanes = consecutive rows, fixed slot) and writes (row=t>>k) both
// land 2 lanes per bank-quad per 16-lane phase => conflict-free-ish.
__device__ __forceinline__ s16x8* lds_slot(short (*T)[LK], int row, int slot) {
  return (s16x8*)&T[row][(slot ^ ((row >> 1) & 3)) * 8];
}

// 64x128 tile, 4 waves (2Mx2N of 32x64), one K-step of 32
__device__ __forceinline__ void mfma2(short (*As)[LK], short (*Bs)[LK],
                                      f32x4 acc[2][4], int wr, int wc, int lq, int lr) {
  s16x8 av[2], bv[4];
#pragma unroll
  for (int m = 0; m < 2; ++m) av[m] = *lds_slot(As, wr * 32 + m * 16 + lr, lq);
#pragma unroll
  for (int n = 0; n < 4; ++n) bv[n] = *lds_slot(Bs, wc * 64 + n * 16 + lr, lq);
#pragma unroll
  for (int m = 0; m < 2; ++m)
#pragma unroll
    for (int n = 0; n < 4; ++n)
      acc[m][n] = __builtin_amdgcn_mfma_f32_16x16x32_bf16(av[m], bv[n], acc[m][n], 0, 0, 0);
}

// XCD-chunked remap (n divisible by 8): blocks sharing an A-tile stay on one XCD
__device__ __forceinline__ int xcd_remap(int bid, int n) {
  return (bid & 7) * (n >> 3) + (bid >> 3);
}

#define GEMM_PROLOG                                            \
  int t = threadIdx.x, lane = t & 63, wid = t >> 6;            \
  int wr = wid >> 1, wc = wid & 1, lq = lane >> 4, lr = lane & 15; \
  __shared__ short As[64][LK];                                 \
  __shared__ short Bs[128][LK];                                \
  f32x4 acc[2][4];                                             \
  _Pragma("unroll") for (int m = 0; m < 2; ++m)                \
  _Pragma("unroll") for (int n = 0; n < 4; ++n)                \
      acc[m][n] = (f32x4){0.f, 0.f, 0.f, 0.f};                 \
  int ar = t >> 2, as_ = t & 3;   /* A: 64 rows, 1 slot/thread */ \
  int br = t >> 1, bs_ = (t & 1) * 2; /* B: 128 rows, 2 slots */

// ---------------------------------------------------------------------------
// sim: S[b][i][j] = sum_k A[i][k]*A[j][k].  SPLIT=1: Xs [L][1536] hi|lo,
// virtual K=2304: A segs {hi,lo,hi}, B segs {hi,hi,lo} (drops lo*lo only).
// ---------------------------------------------------------------------------
template <int SPLIT>
__global__ __launch_bounds__(256) void k_sim_mfma(const short* __restrict__ X,
                                                  float* __restrict__ Sout) {
  int wg = xcd_remap(blockIdx.x, gridDim.x);
  int jb = wg & 3, ib = (wg >> 2) & 7, b = wg >> 5;
  int i0 = ib * 64, j0 = jb * 128;
  const int ld = SPLIT ? 1536 : D_;
  const short* Xb = X + (size_t)b * L_ * ld;
  GEMM_PROLOG
  const int K = SPLIT ? 2304 : D_;
  for (int k0 = 0; k0 < K; k0 += LK) {
    int seg = SPLIT ? (k0 / 768) : 0;
    int kl = k0 - seg * 768;
    int ak = kl + ((SPLIT && seg == 1) ? 768 : 0);
    int bk = kl + ((SPLIT && seg == 2) ? 768 : 0);
    *lds_slot(As, ar, as_) = *(const s16x8*)&Xb[(size_t)(i0 + ar) * ld + ak + as_ * 8];
    *lds_slot(Bs, br, bs_) = *(const s16x8*)&Xb[(size_t)(j0 + br) * ld + bk + bs_ * 8];
    *lds_slot(Bs, br, bs_ + 1) =
        *(const s16x8*)&Xb[(size_t)(j0 + br) * ld + bk + (bs_ + 1) * 8];
    __syncthreads();
    mfma2(As, Bs, acc, wr, wc, lq, lr);
    __syncthreads();
  }
  float* Cb = Sout + (size_t)b * L_ * L_;
#pragma unroll
  for (int m = 0; m < 2; ++m)
#pragma unroll
    for (int n = 0; n < 4; ++n)
#pragma unroll
      for (int rr = 0; rr < 4; ++rr)
        Cb[(size_t)(i0 + wr * 32 + m * 16 + 4 * lq + rr) * L_ +
           (j0 + wc * 64 + n * 16 + lr)] = acc[m][n][rr];
}

// ---------------------------------------------------------------------------
// conv1d(k=3,pad1) im2col GEMM + bias + relu. X bf16 [L][ldx]; Wt2 bf16 [o][2304].
// Writes Ybf always; Yf (f32) when WF32 (for output 0).
// ---------------------------------------------------------------------------
template <int WF32>
__global__ __launch_bounds__(256) void k_conv_mfma(const short* __restrict__ X, int ldx,
                                                   const short* __restrict__ Wt2,
                                                   const float* __restrict__ bias,
                                                   short* __restrict__ Ybf,
                                                   float* __restrict__ Yf) {
  int wg = xcd_remap(blockIdx.x, gridDim.x);
  int ob = wg % 6;
  int m64 = wg / 6;
  int b = m64 >> 3, l0 = (m64 & 7) * 64, o0 = ob * 128;
  const short* Xb = X + (size_t)b * L_ * ldx;
  GEMM_PROLOG
  const s16x8 z8 = {0, 0, 0, 0, 0, 0, 0, 0};
  for (int k0 = 0; k0 < 3 * D_; k0 += LK) {
    int tap = k0 / D_;
    int kl = k0 - tap * D_;
    int l = l0 + ar + tap - 1;
    s16x8 va = (l >= 0 && l < L_)
                   ? *(const s16x8*)&Xb[(size_t)l * ldx + kl + as_ * 8]
                   : z8;
    *lds_slot(As, ar, as_) = va;
    *lds_slot(Bs, br, bs_) =
        *(const s16x8*)&Wt2[(size_t)(o0 + br) * (3 * D_) + k0 + bs_ * 8];
    *lds_slot(Bs, br, bs_ + 1) =
        *(const s16x8*)&Wt2[(size_t)(o0 + br) * (3 * D_) + k0 + (bs_ + 1) * 8];
    __syncthreads();
    mfma2(As, Bs, acc, wr, wc, lq, lr);
    __syncthreads();
  }
  float bv[4];
#pragma unroll
  for (int n = 0; n < 4; ++n) bv[n] = bias[o0 + wc * 64 + n * 16 + lr];
#pragma unroll
  for (int m = 0; m < 2; ++m)
#pragma unroll
    for (int n = 0; n < 4; ++n)
#pragma unroll
      for (int rr = 0; rr < 4; ++rr) {
        int l = l0 + wr * 32 + m * 16 + 4 * lq + rr;
        int o = o0 + wc * 64 + n * 16 + lr;
        float v = fmaxf(acc[m][n][rr] + bv[n], 0.f);
        size_t off = ((size_t)b * L_ + l) * D_ + o;
        Ybf[off] = f2bf(v);
        if (WF32) Yf[off] = v;
      }
}

// ---------------------------------------------------------------------------
// att apply: R[b][i][hop][:] = P[b][i][:] * V ; P bf16 [L][L], Vt bf16 [D][L]
// ---------------------------------------------------------------------------
__global__ __launch_bounds__(256) void k_att_mfma(const short* __restrict__ P,
                                                  const short* __restrict__ Vt,
                                                  short* __restrict__ Rb, int hop) {
  int wg = xcd_remap(blockIdx.x, gridDim.x);
  int db = wg % 6;
  int r_ = wg / 6;
  int ib = r_ & 7, b = r_ >> 3;
  int d0 = db * 128, i0 = ib * 64;
  const short* Pb = P + (size_t)b * L_ * L_;
  const short* Vb = Vt + (size_t)b * D_ * L_;
  GEMM_PROLOG
  for (int k0 = 0; k0 < L_; k0 += LK) {
    *lds_slot(As, ar, as_) = *(const s16x8*)&Pb[(size_t)(i0 + ar) * L_ + k0 + as_ * 8];
    *lds_slot(Bs, br, bs_) = *(const s16x8*)&Vb[(size_t)(d0 + br) * L_ + k0 + bs_ * 8];
    *lds_slot(Bs, br, bs_ + 1) =
        *(const s16x8*)&Vb[(size_t)(d0 + br) * L_ + k0 + (bs_ + 1) * 8];
    __syncthreads();
    mfma2(As, Bs, acc, wr, wc, lq, lr);
    __syncthreads();
  }
#pragma unroll
  for (int m = 0; m < 2; ++m)
#pragma unroll
    for (int n = 0; n < 4; ++n)
#pragma unroll
      for (int rr = 0; rr < 4; ++rr) {
        int i = i0 + wr * 32 + m * 16 + 4 * lq + rr;
        int d = d0 + wc * 64 + n * 16 + lr;
        Rb[((size_t)(b * L_ + i) * 4 + hop) * D_ + d] = f2bf(acc[m][n][rr]);
      }
}

// ---------------------------------------------------------------------------
// pool GEMM + tanh·w2 epilogue; Rb bf16 [32768][768], W1t bf16 [768][768]
// ---------------------------------------------------------------------------
__global__ __launch_bounds__(256) void k_pool_mfma(const short* __restrict__ Rb,
                                                   const short* __restrict__ W1t,
                                                   const float* __restrict__ b1,
                                                   const float* __restrict__ w2,
                                                   float* __restrict__ ps) {
  int wg = xcd_remap(blockIdx.x, gridDim.x);
  int eb = wg % 6;
  int r64 = wg / 6;
  int e0 = eb * 128, r0 = r64 * 64;
  GEMM_PROLOG
  for (int k0 = 0; k0 < D_; k0 += LK) {
    *lds_slot(As, ar, as_) = *(const s16x8*)&Rb[(size_t)(r0 + ar) * D_ + k0 + as_ * 8];
    *lds_slot(Bs, br, bs_) = *(const s16x8*)&W1t[(size_t)(e0 + br) * D_ + k0 + bs_ * 8];
    *lds_slot(Bs, br, bs_ + 1) =
        *(const s16x8*)&W1t[(size_t)(e0 + br) * D_ + k0 + (bs_ + 1) * 8];
    __syncthreads();
    mfma2(As, Bs, acc, wr, wc, lq, lr);
    __syncthreads();
  }
  float b1v[4], w2v[4];
#pragma unroll
  for (int n = 0; n < 4; ++n) {
    int e = e0 + wc * 64 + n * 16 + lr;
    b1v[n] = b1[e];
    w2v[n] = w2[e];
  }
#pragma unroll
  for (int m = 0; m < 2; ++m)
#pragma unroll
    for (int rr = 0; rr < 4; ++rr) {
      float p = 0.f;
#pragma unroll
      for (int n = 0; n < 4; ++n) p += tanhf(acc[m][n][rr] + b1v[n]) * w2v[n];
      p += __shfl_xor(p, 1);
      p += __shfl_xor(p, 2);
      p += __shfl_xor(p, 4);
      p += __shfl_xor(p, 8);
      if (lr == 0) atomicAdd(&ps[r0 + wr * 32 + m * 16 + 4 * lq + rr], p);
    }
}

// ---------------------------------------------------------------------------
// bf16 transpose: in [L][ld] -> outT [D][L] (per batch)
// ---------------------------------------------------------------------------
__global__ __launch_bounds__(256) void k_transp(const short* __restrict__ in, int ld,
                                                short* __restrict__ outT) {
  int l0 = blockIdx.x * 32, d0 = blockIdx.y * 32, b = blockIdx.z;
  __shared__ short tile[32][34];
  int r = threadIdx.x >> 5, c = threadIdx.x & 31;
  const short* ib = in + (size_t)b * L_ * ld;
#pragma unroll
  for (int i = 0; i < 4; ++i)
    tile[r + 8 * i][c] = ib[(size_t)(l0 + r + 8 * i) * ld + d0 + c];
  __syncthreads();
  short* ob = outT + (size_t)b * D_ * L_;
#pragma unroll
  for (int i = 0; i < 4; ++i)
    ob[(size_t)(d0 + r + 8 * i) * L_ + l0 + c] = tile[c][r + 8 * i];
}

// ---------------------------------------------------------------------------
// softmask: S f32 -> P bf16 (with optional cosine row-norm division)
// ---------------------------------------------------------------------------
__global__ __launch_bounds__(256) void k_softmask2(const float* __restrict__ S,
                                                   const float* __restrict__ mask,
                                                   const float* __restrict__ rn,
                                                   short* __restrict__ P) {
  int b = blockIdx.y, i = blockIdx.x;
  const float* row = S + ((size_t)b * L_ + i) * L_;
  short* prow = P + ((size_t)b * L_ + i) * L_;
  const float* mb = mask + (size_t)b * L_;
  int t = threadIdx.x;
  float v0 = row[t], v1 = row[t + 256];
  if (rn) {
    float inv_ri = 1.f / rn[(size_t)b * L_ + i];
    v0 *= inv_ri / rn[(size_t)b * L_ + t];
    v1 *= inv_ri / rn[(size_t)b * L_ + t + 256];
  }
  __shared__ float red[256];
  red[t] = fmaxf(v0, v1);
  __syncthreads();
  for (int s = 128; s > 0; s >>= 1) {
    if (t < s) red[t] = fmaxf(red[t], red[t + s]);
    __syncthreads();
  }
  float m = red[0];
  __syncthreads();
  float y0 = __expf(v0 - m) * mb[t];
  float y1 = __expf(v1 - m) * mb[t + 256];
  red[t] = y0 + y1;
  __syncthreads();
  for (int s = 128; s > 0; s >>= 1) {
    if (t < s) red[t] += red[t + s];
    __syncthreads();
  }
  float inv = 1.f / (red[0] + 1e-10f);
  float mi = mb[i];
  prow[t] = f2bf(y0 * inv * mi);
  prow[t + 256] = f2bf(y1 * inv * mi);
}

// row L2 norms from bf16 activations
__global__ __launch_bounds__(256) void k_rownorm_bf(const short* __restrict__ X,
                                                    float* __restrict__ rn) {
  int b = blockIdx.y, l = blockIdx.x;
  const short* row = X + ((size_t)b * L_ + l) * D_;
  int t = threadIdx.x;
  float s = 0.f;
  for (int d = t; d < D_; d += 256) {
    float v = bf2f(row[d]);
    s += v * v;
  }
  __shared__ float red[256];
  red[t] = s;
  __syncthreads();
  for (int st = 128; st > 0; st >>= 1) {
    if (t < st) red[t] += red[t + st];
    __syncthreads();
  }
  if (t == 0) rn[(size_t)b * L_ + l] = fmaxf(sqrtf(red[0]), 1e-12f);
}

// inputs f32 -> Xs bf16 [B*L][1536] = [hi | lo]
__global__ void k_prep(const float* __restrict__ in, short* __restrict__ Xs) {
  size_t idx = (size_t)blockIdx.x * 256 + threadIdx.x;
  if (idx >= (size_t)B_ * L_ * D_) return;
  size_t bl = idx / D_;
  int d = (int)(idx % D_);
  float x = in[idx];
  short hi = f2bf(x);
  short lo = f2bf(x - bf2f(hi));
  Xs[bl * 1536 + d] = hi;
  Xs[bl * 1536 + 768 + d] = lo;
}

// conv_w [h][o][i][kk] -> Wt2 bf16 [h][o][kk*768+i]
__global__ void k_wtrans2(const float* __restrict__ w, short* __restrict__ Wt2) {
  size_t idx = (size_t)blockIdx.x * 256 + threadIdx.x;
  const size_t total = (size_t)HOPS_ * D_ * 3 * D_;
  if (idx >= total) return;
  int i = (int)(idx % D_);
  size_t tmp = idx / D_;
  int kk = (int)(tmp % 3);
  tmp /= 3;
  int o = (int)(tmp % D_);
  int h = (int)(tmp / D_);
  Wt2[idx] = f2bf(w[(((size_t)h * D_ + o) * D_ + i) * 3 + kk]);
}

// W1 [d][e] -> W1t bf16 [e][d]
__global__ void k_w1t(const float* __restrict__ W1, short* __restrict__ W1t) {
  size_t idx = (size_t)blockIdx.x * 256 + threadIdx.x;
  if (idx >= (size_t)D_ * D_) return;
  int e = (int)(idx / D_), d = (int)(idx % D_);
  W1t[idx] = f2bf(W1[(size_t)d * D_ + e]);
}

// out[b][l][d] = sum_h softmax(ps)[h] * Rb[bl][h][d]
__global__ __launch_bounds__(256) void k_weighted2(const short* __restrict__ Rb,
                                                   const float* __restrict__ ps,
                                                   float* __restrict__ out) {
  int b = blockIdx.y, l = blockIdx.x;
  size_t bl = (size_t)b * L_ + l;
  const float* p = ps + bl * 4;
  float s0 = p[0], s1 = p[1], s2 = p[2], s3 = p[3];
  float m = fmaxf(fmaxf(s0, s1), fmaxf(s2, s3));
  float e0 = __expf(s0 - m), e1 = __expf(s1 - m), e2 = __expf(s2 - m),
        e3 = __expf(s3 - m);
  float inv = 1.f / (e0 + e1 + e2 + e3);
  e0 *= inv; e1 *= inv; e2 *= inv; e3 *= inv;
  const short* Rrow = Rb + bl * 4 * D_;
  float* orow = out + bl * D_;
  for (int d = threadIdx.x; d < D_; d += 256) {
    orow[d] = e0 * bf2f(Rrow[d]) + e1 * bf2f(Rrow[D_ + d]) +
              e2 * bf2f(Rrow[2 * D_ + d]) + e3 * bf2f(Rrow[3 * D_ + d]);
  }
}

extern "C" void kernel_launch(void* const* d_in, const int* in_sizes, int n_in,
                              void* d_out, int out_size, void* d_ws, size_t ws_size,
                              hipStream_t stream) {
  const float* inputs  = (const float*)d_in[0];
  const float* mask    = (const float*)d_in[1];
  const float* conv_w  = (const float*)d_in[2];
  const float* conv_b  = (const float*)d_in[3];
  const float* pool_w1 = (const float*)d_in[4];
  const float* pool_b1 = (const float*)d_in[5];
  const float* pool_w2 = (const float*)d_in[6];
  float* out = (float*)d_out;

  const size_t BLD = (size_t)B_ * L_ * D_;
  const size_t BLL = (size_t)B_ * L_ * L_;

  char* w = (char*)d_ws;
  short* Xs   = (short*)w; w += (size_t)2 * BLD * 2;               // 25.2 MB [hi|lo]
  short* Wt2  = (short*)w; w += (size_t)HOPS_ * 3 * D_ * D_ * 2;   // 10.6 MB
  short* W1t  = (short*)w; w += (size_t)D_ * D_ * 2;               // 1.2 MB
  float* S    = (float*)w; w += BLL * 4;                           // 16.8 MB
  short* Pb   = (short*)w; w += BLL * 2;                           // 8.4 MB
  short* YbfA = (short*)w; w += BLD * 2;                           // 12.6 MB
  short* YbfB = (short*)w; w += BLD * 2;                           // 12.6 MB
  short* Vt   = (short*)w; w += BLD * 2;                           // 12.6 MB
  short* Rb   = (short*)w; w += 4 * BLD * 2;                       // 50.3 MB
  float* rn   = (float*)w; w += (size_t)B_ * L_ * 4;
  float* ps   = (float*)w; w += (size_t)B_ * L_ * 4 * 4;
  float* Yf   = (float*)Xs;  // alias: Xs dead by hop 2 (only h==2 writes Yf)

  // --- prep ---
  k_prep<<<dim3((unsigned)((BLD + 255) / 256)), 256, 0, stream>>>(inputs, Xs);
  {
    size_t tot = (size_t)HOPS_ * D_ * 3 * D_;
    k_wtrans2<<<dim3((unsigned)((tot + 255) / 256)), 256, 0, stream>>>(conv_w, Wt2);
  }
  k_w1t<<<dim3((unsigned)(((size_t)D_ * D_ + 255) / 256)), 256, 0, stream>>>(pool_w1, W1t);

  dim3 gtr(L_ / 32, D_ / 32, B_);   // transpose
  dim3 grow(L_, B_);
  const int GSIM = (L_ / 64) * (L_ / 128) * B_;   // 512
  const int GCONV = (D_ / 128) * (B_ * L_ / 64);  // 768
  const int GATT = GCONV;                          // 768
  const int GPOOL = (D_ / 128) * (4 * B_ * L_ / 64);  // 3072

  // --- hop 0: split-bf16 similarity on raw inputs ---
  k_transp<<<gtr, 256, 0, stream>>>(Xs, 1536, Vt);
  k_sim_mfma<1><<<GSIM, 256, 0, stream>>>(Xs, S);
  k_softmask2<<<grow, 256, 0, stream>>>(S, mask, nullptr, Pb);
  k_att_mfma<<<GATT, 256, 0, stream>>>(Pb, Vt, Rb, 0);

  // --- hops 1..3 ---
  const short* cur = Xs;
  int ldc = 1536;
  for (int h = 0; h < HOPS_; ++h) {
    short* cv = (h & 1) ? YbfB : YbfA;  // h0->A, h1->B, h2->A
    const short* Wh = Wt2 + (size_t)h * 3 * D_ * D_;
    const float* bh = conv_b + (size_t)h * D_;
    if (h == HOPS_ - 1)
      k_conv_mfma<1><<<GCONV, 256, 0, stream>>>(cur, ldc, Wh, bh, cv, Yf);
    else
      k_conv_mfma<0><<<GCONV, 256, 0, stream>>>(cur, ldc, Wh, bh, cv, nullptr);
    k_rownorm_bf<<<grow, 256, 0, stream>>>(cv, rn);
    k_transp<<<gtr, 256, 0, stream>>>(cv, D_, Vt);
    k_sim_mfma<0><<<GSIM, 256, 0, stream>>>(cv, S);
    k_softmask2<<<grow, 256, 0, stream>>>(S, mask, rn, Pb);
    k_att_mfma<<<GATT, 256, 0, stream>>>(Pb, Vt, Rb, h + 1);
    cur = cv;
    ldc = D_;
  }

  // --- pooling ---
  hipMemsetAsync(ps, 0, (size_t)B_ * L_ * 4 * sizeof(float), stream);
  k_pool_mfma<<<GPOOL, 256, 0, stream>>>(Rb, W1t, pool_b1, pool_w2, ps);
  k_weighted2<<<grow, 256, 0, stream>>>(Rb, ps, out + BLD);

  // output 0: final conv activation (f32)
  hipMemcpyAsync(out, Yf, BLD * sizeof(float), hipMemcpyDeviceToDevice, stream);
}

// Round 4
// 585.029 us; speedup vs baseline: 6.4265x; 1.1008x over previous
//
#include <hip/hip_runtime.h>
#include <math.h>

#define B_ 16
#define L_ 512
#define D_ 768
#define HOPS_ 3
#define LK 64  // shorts per LDS row = 128B = 8 swizzled 16B slots

typedef __attribute__((ext_vector_type(8))) short s16x8;
typedef __attribute__((ext_vector_type(4))) short s16x4;
typedef __attribute__((ext_vector_type(4))) float f32x4;

__device__ __forceinline__ short f2bf(float f) {
  unsigned u = __float_as_uint(f);
  unsigned r = (u + 0x7fffu + ((u >> 16) & 1u)) >> 16;
  return (short)r;
}
__device__ __forceinline__ float bf2f(short s) {
  unsigned u = ((unsigned)(unsigned short)s) << 16;
  return __uint_as_float(u);
}
__device__ __forceinline__ float tanh_fast(float x) {
  float e = __expf(2.f * x);        // inf-safe: +inf -> 1, 0 -> -1
  return 1.f - 2.f / (e + 1.f);
}

// phys slot = slot ^ (row&7): rows stride 128B (bank-aliased); XOR spreads a
// 16-row fragment read over 8 distinct 16B slots (2 lanes/bank = free) and
// keeps writes uniform. Verified round 3: SQ_LDS_BANK_CONFLICT == 0.
__device__ __forceinline__ s16x8* lds_slot(short (*T)[LK], int row, int slot) {
  return (s16x8*)&T[row][(slot ^ (row & 7)) * 8];
}

// 128x128 tile, 4 waves (2x2 of 64x64), K-step 64: 32 MFMA / 8 reads per wave-substep
__device__ __forceinline__ void mfma4(short (*As)[LK], short (*Bs)[LK],
                                      f32x4 acc[4][4], int wr, int wc, int lq, int lr) {
#pragma unroll
  for (int ks = 0; ks < 2; ++ks) {
    int sl = ks * 4 + lq;
    s16x8 av[4], bv[4];
#pragma unroll
    for (int m = 0; m < 4; ++m) av[m] = *lds_slot(As, wr * 64 + m * 16 + lr, sl);
#pragma unroll
    for (int n = 0; n < 4; ++n) bv[n] = *lds_slot(Bs, wc * 64 + n * 16 + lr, sl);
#pragma unroll
    for (int m = 0; m < 4; ++m)
#pragma unroll
      for (int n = 0; n < 4; ++n)
        acc[m][n] = __builtin_amdgcn_mfma_f32_16x16x32_bf16(av[m], bv[n], acc[m][n], 0, 0, 0);
  }
}

// 64x128 tile, 4 waves (2x2 of 32x64), K-step 64 (sim keeps 2 blocks/CU TLP)
__device__ __forceinline__ void mfma2(short (*As)[LK], short (*Bs)[LK],
                                      f32x4 acc[2][4], int wr, int wc, int lq, int lr) {
#pragma unroll
  for (int ks = 0; ks < 2; ++ks) {
    int sl = ks * 4 + lq;
    s16x8 av[2], bv[4];
#pragma unroll
    for (int m = 0; m < 2; ++m) av[m] = *lds_slot(As, wr * 32 + m * 16 + lr, sl);
#pragma unroll
    for (int n = 0; n < 4; ++n) bv[n] = *lds_slot(Bs, wc * 64 + n * 16 + lr, sl);
#pragma unroll
    for (int m = 0; m < 2; ++m)
#pragma unroll
      for (int n = 0; n < 4; ++n)
        acc[m][n] = __builtin_amdgcn_mfma_f32_16x16x32_bf16(av[m], bv[n], acc[m][n], 0, 0, 0);
  }
}

// XCD-chunked remap (n % 8 == 0): contiguous logical chunk per XCD
__device__ __forceinline__ int xcd_remap(int bid, int n) {
  return (bid & 7) * (n >> 3) + (bid >> 3);
}

// ---------------------------------------------------------------------------
// sim: S[b][i][j] = sum_k A[i][k]*A[j][k].  SPLIT=1: Xs [L][1536] hi|lo,
// virtual K=2304: A segs {hi,lo,hi}, B segs {hi,hi,lo} (drops only lo*lo).
// 64x128 tile.
// ---------------------------------------------------------------------------
template <int SPLIT>
__global__ __launch_bounds__(256) void k_sim_mfma(const short* __restrict__ X,
                                                  float* __restrict__ Sout) {
  int wg = xcd_remap(blockIdx.x, gridDim.x);
  int jb = wg & 3, ib = (wg >> 2) & 7, b = wg >> 5;
  int i0 = ib * 64, j0 = jb * 128;
  const int ld = SPLIT ? 1536 : D_;
  const short* Xb = X + (size_t)b * L_ * ld;
  int t = threadIdx.x, lane = t & 63, wid = t >> 6;
  int wr = wid >> 1, wc = wid & 1, lq = lane >> 4, lr = lane & 15;
  __shared__ short As[64][LK];
  __shared__ short Bs[128][LK];
  f32x4 acc[2][4];
#pragma unroll
  for (int m = 0; m < 2; ++m)
#pragma unroll
    for (int n = 0; n < 4; ++n) acc[m][n] = (f32x4){0.f, 0.f, 0.f, 0.f};
  int ar = t >> 2, ah = (t & 3) * 2;  // A: 64 rows, 2 slots/thread
  int br = t >> 1, bh = (t & 1) * 4;  // B: 128 rows, 4 slots/thread
  const int K = SPLIT ? 2304 : D_;
  for (int k0 = 0; k0 < K; k0 += LK) {
    int seg = SPLIT ? (k0 / 768) : 0;
    int kl = k0 - seg * 768;
    int ak = kl + ((SPLIT && seg == 1) ? 768 : 0);
    int bk = kl + ((SPLIT && seg == 2) ? 768 : 0);
    const short* pa = Xb + (size_t)(i0 + ar) * ld + ak;
    const short* pb = Xb + (size_t)(j0 + br) * ld + bk;
#pragma unroll
    for (int i = 0; i < 2; ++i)
      *lds_slot(As, ar, ah + i) = *(const s16x8*)(pa + (ah + i) * 8);
#pragma unroll
    for (int i = 0; i < 4; ++i)
      *lds_slot(Bs, br, bh + i) = *(const s16x8*)(pb + (bh + i) * 8);
    __syncthreads();
    mfma2(As, Bs, acc, wr, wc, lq, lr);
    __syncthreads();
  }
  float* Cb = Sout + (size_t)b * L_ * L_;
#pragma unroll
  for (int m = 0; m < 2; ++m)
#pragma unroll
    for (int n = 0; n < 4; ++n)
#pragma unroll
      for (int rr = 0; rr < 4; ++rr)
        Cb[(size_t)(i0 + wr * 32 + m * 16 + 4 * lq + rr) * L_ +
           (j0 + wc * 64 + n * 16 + lr)] = acc[m][n][rr];
}

// ---------------------------------------------------------------------------
// conv1d(k=3,pad1) im2col GEMM + bias + relu. 128x128 tile.
// X bf16 [L][ldx]; Wt2 bf16 [o][2304]. Writes Ybf; f32 to Yf when WF32.
// Also accumulates per-row sum-of-squares into rnsq (pre-zeroed).
// ---------------------------------------------------------------------------
template <int WF32>
__global__ __launch_bounds__(256) void k_conv_mfma(const short* __restrict__ X, int ldx,
                                                   const short* __restrict__ Wt2,
                                                   const float* __restrict__ bias,
                                                   short* __restrict__ Ybf,
                                                   float* __restrict__ Yf,
                                                   float* __restrict__ rnsq) {
  int wg = xcd_remap(blockIdx.x, gridDim.x);
  int ob = wg % 6;
  int m_ = wg / 6;
  int b = m_ >> 2, l0 = (m_ & 3) * 128, o0 = ob * 128;
  const short* Xb = X + (size_t)b * L_ * ldx;
  int t = threadIdx.x, lane = t & 63, wid = t >> 6;
  int wr = wid >> 1, wc = wid & 1, lq = lane >> 4, lr = lane & 15;
  __shared__ short As[128][LK];
  __shared__ short Bs[128][LK];
  f32x4 acc[4][4];
#pragma unroll
  for (int m = 0; m < 4; ++m)
#pragma unroll
    for (int n = 0; n < 4; ++n) acc[m][n] = (f32x4){0.f, 0.f, 0.f, 0.f};
  int r_ = t >> 1, h_ = (t & 1) * 4;  // 128 rows, 4 slots/thread (A and B)
  const s16x8 z8 = {0, 0, 0, 0, 0, 0, 0, 0};
  for (int k0 = 0; k0 < 3 * D_; k0 += LK) {
    int tap = k0 / D_;
    int kl = k0 - tap * D_;
    int l = l0 + r_ + tap - 1;
    const short* pa = Xb + (size_t)l * ldx + kl;
    const short* pb = Wt2 + (size_t)(o0 + r_) * (3 * D_) + k0;
    bool ok = (l >= 0 && l < L_);
#pragma unroll
    for (int i = 0; i < 4; ++i)
      *lds_slot(As, r_, h_ + i) = ok ? *(const s16x8*)(pa + (h_ + i) * 8) : z8;
#pragma unroll
    for (int i = 0; i < 4; ++i)
      *lds_slot(Bs, r_, h_ + i) = *(const s16x8*)(pb + (h_ + i) * 8);
    __syncthreads();
    mfma4(As, Bs, acc, wr, wc, lq, lr);
    __syncthreads();
  }
  float bv[4];
#pragma unroll
  for (int n = 0; n < 4; ++n) bv[n] = bias[o0 + wc * 64 + n * 16 + lr];
#pragma unroll
  for (int m = 0; m < 4; ++m)
#pragma unroll
    for (int rr = 0; rr < 4; ++rr) {
      int l = l0 + wr * 64 + m * 16 + 4 * lq + rr;
      size_t rowoff = ((size_t)b * L_ + l) * D_;
      float ss = 0.f;
#pragma unroll
      for (int n = 0; n < 4; ++n) {
        int o = o0 + wc * 64 + n * 16 + lr;
        float v = fmaxf(acc[m][n][rr] + bv[n], 0.f);
        Ybf[rowoff + o] = f2bf(v);
        if (WF32) Yf[rowoff + o] = v;
        ss += v * v;
      }
      ss += __shfl_xor(ss, 1);
      ss += __shfl_xor(ss, 2);
      ss += __shfl_xor(ss, 4);
      ss += __shfl_xor(ss, 8);
      if (lr == 0) atomicAdd(&rnsq[(size_t)b * L_ + l], ss);
    }
}

// ---------------------------------------------------------------------------
// att apply: R[b][i][hop][:] = P[b][i][:]*V; P bf16 [L][L], Vt bf16 [D][L].
// 128x128 tile.
// ---------------------------------------------------------------------------
__global__ __launch_bounds__(256) void k_att_mfma(const short* __restrict__ P,
                                                  const short* __restrict__ Vt,
                                                  short* __restrict__ Rb, int hop) {
  int wg = xcd_remap(blockIdx.x, gridDim.x);
  int db = wg % 6;
  int r2 = wg / 6;
  int b = r2 >> 2, i0 = (r2 & 3) * 128, d0 = db * 128;
  const short* Pb = P + (size_t)b * L_ * L_;
  const short* Vb = Vt + (size_t)b * D_ * L_;
  int t = threadIdx.x, lane = t & 63, wid = t >> 6;
  int wr = wid >> 1, wc = wid & 1, lq = lane >> 4, lr = lane & 15;
  __shared__ short As[128][LK];
  __shared__ short Bs[128][LK];
  f32x4 acc[4][4];
#pragma unroll
  for (int m = 0; m < 4; ++m)
#pragma unroll
    for (int n = 0; n < 4; ++n) acc[m][n] = (f32x4){0.f, 0.f, 0.f, 0.f};
  int r_ = t >> 1, h_ = (t & 1) * 4;
  for (int k0 = 0; k0 < L_; k0 += LK) {
    const short* pa = Pb + (size_t)(i0 + r_) * L_ + k0;
    const short* pb = Vb + (size_t)(d0 + r_) * L_ + k0;
#pragma unroll
    for (int i = 0; i < 4; ++i)
      *lds_slot(As, r_, h_ + i) = *(const s16x8*)(pa + (h_ + i) * 8);
#pragma unroll
    for (int i = 0; i < 4; ++i)
      *lds_slot(Bs, r_, h_ + i) = *(const s16x8*)(pb + (h_ + i) * 8);
    __syncthreads();
    mfma4(As, Bs, acc, wr, wc, lq, lr);
    __syncthreads();
  }
#pragma unroll
  for (int m = 0; m < 4; ++m)
#pragma unroll
    for (int n = 0; n < 4; ++n)
#pragma unroll
      for (int rr = 0; rr < 4; ++rr) {
        int i = i0 + wr * 64 + m * 16 + 4 * lq + rr;
        int d = d0 + wc * 64 + n * 16 + lr;
        Rb[((size_t)(b * L_ + i) * 4 + hop) * D_ + d] = f2bf(acc[m][n][rr]);
      }
}

// ---------------------------------------------------------------------------
// pool GEMM + fast-tanh·w2 epilogue. 128x128 tile. Rb [32768][768] bf16.
// ---------------------------------------------------------------------------
__global__ __launch_bounds__(256) void k_pool_mfma(const short* __restrict__ Rb,
                                                   const short* __restrict__ W1t,
                                                   const float* __restrict__ b1,
                                                   const float* __restrict__ w2,
                                                   float* __restrict__ ps) {
  int wg = xcd_remap(blockIdx.x, gridDim.x);
  int eb = wg % 6;
  int r0 = (wg / 6) * 128, e0 = eb * 128;
  int t = threadIdx.x, lane = t & 63, wid = t >> 6;
  int wr = wid >> 1, wc = wid & 1, lq = lane >> 4, lr = lane & 15;
  __shared__ short As[128][LK];
  __shared__ short Bs[128][LK];
  f32x4 acc[4][4];
#pragma unroll
  for (int m = 0; m < 4; ++m)
#pragma unroll
    for (int n = 0; n < 4; ++n) acc[m][n] = (f32x4){0.f, 0.f, 0.f, 0.f};
  int r_ = t >> 1, h_ = (t & 1) * 4;
  for (int k0 = 0; k0 < D_; k0 += LK) {
    const short* pa = Rb + (size_t)(r0 + r_) * D_ + k0;
    const short* pb = W1t + (size_t)(e0 + r_) * D_ + k0;
#pragma unroll
    for (int i = 0; i < 4; ++i)
      *lds_slot(As, r_, h_ + i) = *(const s16x8*)(pa + (h_ + i) * 8);
#pragma unroll
    for (int i = 0; i < 4; ++i)
      *lds_slot(Bs, r_, h_ + i) = *(const s16x8*)(pb + (h_ + i) * 8);
    __syncthreads();
    mfma4(As, Bs, acc, wr, wc, lq, lr);
    __syncthreads();
  }
  float b1v[4], w2v[4];
#pragma unroll
  for (int n = 0; n < 4; ++n) {
    int e = e0 + wc * 64 + n * 16 + lr;
    b1v[n] = b1[e];
    w2v[n] = w2[e];
  }
#pragma unroll
  for (int m = 0; m < 4; ++m)
#pragma unroll
    for (int rr = 0; rr < 4; ++rr) {
      float p = 0.f;
#pragma unroll
      for (int n = 0; n < 4; ++n) p += tanh_fast(acc[m][n][rr] + b1v[n]) * w2v[n];
      p += __shfl_xor(p, 1);
      p += __shfl_xor(p, 2);
      p += __shfl_xor(p, 4);
      p += __shfl_xor(p, 8);
      if (lr == 0) atomicAdd(&ps[r0 + wr * 64 + m * 16 + 4 * lq + rr], p);
    }
}

// ---------------------------------------------------------------------------
// bf16 transpose: in [L][ld] -> outT [D][L] (per batch)
// ---------------------------------------------------------------------------
__global__ __launch_bounds__(256) void k_transp(const short* __restrict__ in, int ld,
                                                short* __restrict__ outT) {
  int l0 = blockIdx.x * 32, d0 = blockIdx.y * 32, b = blockIdx.z;
  __shared__ short tile[32][34];
  int r = threadIdx.x >> 5, c = threadIdx.x & 31;
  const short* ib = in + (size_t)b * L_ * ld;
#pragma unroll
  for (int i = 0; i < 4; ++i)
    tile[r + 8 * i][c] = ib[(size_t)(l0 + r + 8 * i) * ld + d0 + c];
  __syncthreads();
  short* ob = outT + (size_t)b * D_ * L_;
#pragma unroll
  for (int i = 0; i < 4; ++i)
    ob[(size_t)(d0 + r + 8 * i) * L_ + l0 + c] = tile[c][r + 8 * i];
}

// ---------------------------------------------------------------------------
// softmask: one wave per row, no __syncthreads. S f32 -> P bf16.
// NORM: divide by max(sqrt(rsq_i),1e-12)*max(sqrt(rsq_j),1e-12).
// Row max over raw (unmasked) values per reference.
// ---------------------------------------------------------------------------
template <int NORM>
__global__ __launch_bounds__(256) void k_softmask3(const float* __restrict__ S,
                                                   const float* __restrict__ mask,
                                                   const float* __restrict__ rsq,
                                                   short* __restrict__ P) {
  int b = blockIdx.y;
  int i = blockIdx.x * 4 + (threadIdx.x >> 6);
  int l = threadIdx.x & 63;
  const float* row = S + ((size_t)b * L_ + i) * L_;
  const float* mb = mask + (size_t)b * L_;
  float v[8], mk[8];
  {
    float4 s0 = ((const float4*)row)[l * 2];
    float4 s1 = ((const float4*)row)[l * 2 + 1];
    float4 m0 = ((const float4*)mb)[l * 2];
    float4 m1 = ((const float4*)mb)[l * 2 + 1];
    v[0] = s0.x; v[1] = s0.y; v[2] = s0.z; v[3] = s0.w;
    v[4] = s1.x; v[5] = s1.y; v[6] = s1.z; v[7] = s1.w;
    mk[0] = m0.x; mk[1] = m0.y; mk[2] = m0.z; mk[3] = m0.w;
    mk[4] = m1.x; mk[5] = m1.y; mk[6] = m1.z; mk[7] = m1.w;
  }
  if (NORM) {
    float ri = 1.f / fmaxf(sqrtf(rsq[(size_t)b * L_ + i]), 1e-12f);
    const float4* rq = (const float4*)(rsq + (size_t)b * L_);
    float4 q0 = rq[l * 2], q1 = rq[l * 2 + 1];
    float qq[8] = {q0.x, q0.y, q0.z, q0.w, q1.x, q1.y, q1.z, q1.w};
#pragma unroll
    for (int e = 0; e < 8; ++e) v[e] *= ri / fmaxf(sqrtf(qq[e]), 1e-12f);
  }
  float m = v[0];
#pragma unroll
  for (int e = 1; e < 8; ++e) m = fmaxf(m, v[e]);
#pragma unroll
  for (int s = 1; s < 64; s <<= 1) m = fmaxf(m, __shfl_xor(m, s));
  float y[8], sum = 0.f;
#pragma unroll
  for (int e = 0; e < 8; ++e) {
    y[e] = __expf(v[e] - m) * mk[e];
    sum += y[e];
  }
#pragma unroll
  for (int s = 1; s < 64; s <<= 1) sum += __shfl_xor(sum, s);
  float inv = mb[i] / (sum + 1e-10f);
  s16x8 pk;
#pragma unroll
  for (int e = 0; e < 8; ++e) pk[e] = f2bf(y[e] * inv);
  ((s16x8*)(P + ((size_t)b * L_ + i) * L_))[l] = pk;
}

// inputs f32 -> Xs bf16 [B*L][1536] = [hi | lo], 4 elems/thread
__global__ void k_prep4(const float* __restrict__ in, short* __restrict__ Xs) {
  size_t idx = (size_t)blockIdx.x * 256 + threadIdx.x;
  if (idx >= (size_t)B_ * L_ * D_ / 4) return;
  float4 x = ((const float4*)in)[idx];
  size_t base = idx * 4;
  size_t bl = base / D_;
  int d = (int)(base % D_);
  float xs[4] = {x.x, x.y, x.z, x.w};
  s16x4 hi, lo;
#pragma unroll
  for (int e = 0; e < 4; ++e) {
    hi[e] = f2bf(xs[e]);
    lo[e] = f2bf(xs[e] - bf2f(hi[e]));
  }
  *(s16x4*)&Xs[bl * 1536 + d] = hi;
  *(s16x4*)&Xs[bl * 1536 + 768 + d] = lo;
}

// conv_w [h][o][i][kk] -> Wt2 bf16 [h][o][kk*768+i]
__global__ void k_wtrans2(const float* __restrict__ w, short* __restrict__ Wt2) {
  size_t idx = (size_t)blockIdx.x * 256 + threadIdx.x;
  const size_t total = (size_t)HOPS_ * D_ * 3 * D_;
  if (idx >= total) return;
  int i = (int)(idx % D_);
  size_t tmp = idx / D_;
  int kk = (int)(tmp % 3);
  tmp /= 3;
  int o = (int)(tmp % D_);
  int h = (int)(tmp / D_);
  Wt2[idx] = f2bf(w[(((size_t)h * D_ + o) * D_ + i) * 3 + kk]);
}

// W1 [d][e] -> W1t bf16 [e][d]
__global__ void k_w1t(const float* __restrict__ W1, short* __restrict__ W1t) {
  size_t idx = (size_t)blockIdx.x * 256 + threadIdx.x;
  if (idx >= (size_t)D_ * D_) return;
  int e = (int)(idx / D_), d = (int)(idx % D_);
  W1t[idx] = f2bf(W1[(size_t)d * D_ + e]);
}

// out[b][l][d] = sum_h softmax(ps)[h] * Rb[bl][h][d]
__global__ __launch_bounds__(256) void k_weighted2(const short* __restrict__ Rb,
                                                   const float* __restrict__ ps,
                                                   float* __restrict__ out) {
  int b = blockIdx.y, l = blockIdx.x;
  size_t bl = (size_t)b * L_ + l;
  const float* p = ps + bl * 4;
  float s0 = p[0], s1 = p[1], s2 = p[2], s3 = p[3];
  float m = fmaxf(fmaxf(s0, s1), fmaxf(s2, s3));
  float e0 = __expf(s0 - m), e1 = __expf(s1 - m), e2 = __expf(s2 - m),
        e3 = __expf(s3 - m);
  float inv = 1.f / (e0 + e1 + e2 + e3);
  e0 *= inv; e1 *= inv; e2 *= inv; e3 *= inv;
  const short* Rrow = Rb + bl * 4 * D_;
  float* orow = out + bl * D_;
  for (int d = threadIdx.x; d < D_; d += 256) {
    orow[d] = e0 * bf2f(Rrow[d]) + e1 * bf2f(Rrow[D_ + d]) +
              e2 * bf2f(Rrow[2 * D_ + d]) + e3 * bf2f(Rrow[3 * D_ + d]);
  }
}

extern "C" void kernel_launch(void* const* d_in, const int* in_sizes, int n_in,
                              void* d_out, int out_size, void* d_ws, size_t ws_size,
                              hipStream_t stream) {
  const float* inputs  = (const float*)d_in[0];
  const float* mask    = (const float*)d_in[1];
  const float* conv_w  = (const float*)d_in[2];
  const float* conv_b  = (const float*)d_in[3];
  const float* pool_w1 = (const float*)d_in[4];
  const float* pool_b1 = (const float*)d_in[5];
  const float* pool_w2 = (const float*)d_in[6];
  float* out = (float*)d_out;

  const size_t BLD = (size_t)B_ * L_ * D_;
  const size_t BLL = (size_t)B_ * L_ * L_;

  char* w = (char*)d_ws;
  short* Xs   = (short*)w; w += (size_t)2 * BLD * 2;               // 25.2 MB [hi|lo]
  short* Wt2  = (short*)w; w += (size_t)HOPS_ * 3 * D_ * D_ * 2;   // 10.6 MB
  short* W1t  = (short*)w; w += (size_t)D_ * D_ * 2;               // 1.2 MB
  float* S    = (float*)w; w += BLL * 4;                           // 16.8 MB
  short* Pb   = (short*)w; w += BLL * 2;                           // 8.4 MB
  short* YbfA = (short*)w; w += BLD * 2;                           // 12.6 MB
  short* YbfB = (short*)w; w += BLD * 2;                           // 12.6 MB
  short* Vt   = (short*)w; w += BLD * 2;                           // 12.6 MB
  short* Rb   = (short*)w; w += 4 * BLD * 2;                       // 50.3 MB
  float* rnsq = (float*)w; w += (size_t)B_ * L_ * 4;
  float* ps   = (float*)w; w += (size_t)B_ * L_ * 4 * 4;

  // --- prep ---
  k_prep4<<<dim3((unsigned)((BLD / 4 + 255) / 256)), 256, 0, stream>>>(inputs, Xs);
  {
    size_t tot = (size_t)HOPS_ * D_ * 3 * D_;
    k_wtrans2<<<dim3((unsigned)((tot + 255) / 256)), 256, 0, stream>>>(conv_w, Wt2);
  }
  k_w1t<<<dim3((unsigned)(((size_t)D_ * D_ + 255) / 256)), 256, 0, stream>>>(pool_w1, W1t);

  dim3 gtr(L_ / 32, D_ / 32, B_);
  dim3 gsm(L_ / 4, B_);
  dim3 grow(L_, B_);
  const int GSIM = (L_ / 64) * (L_ / 128) * B_;        // 512
  const int GCONV = (D_ / 128) * (L_ / 128) * B_;      // 384
  const int GATT = GCONV;                              // 384
  const int GPOOL = (D_ / 128) * (4 * B_ * L_ / 128);  // 1536

  // --- hop 0: split-bf16 similarity on raw inputs ---
  k_transp<<<gtr, 256, 0, stream>>>(Xs, 1536, Vt);
  k_sim_mfma<1><<<GSIM, 256, 0, stream>>>(Xs, S);
  k_softmask3<0><<<gsm, 256, 0, stream>>>(S, mask, nullptr, Pb);
  k_att_mfma<<<GATT, 256, 0, stream>>>(Pb, Vt, Rb, 0);

  // --- hops 1..3 ---
  const short* cur = Xs;
  int ldc = 1536;
  for (int h = 0; h < HOPS_; ++h) {
    short* cv = (h & 1) ? YbfB : YbfA;
    const short* Wh = Wt2 + (size_t)h * 3 * D_ * D_;
    const float* bh = conv_b + (size_t)h * D_;
    hipMemsetAsync(rnsq, 0, (size_t)B_ * L_ * sizeof(float), stream);
    if (h == HOPS_ - 1)
      k_conv_mfma<1><<<GCONV, 256, 0, stream>>>(cur, ldc, Wh, bh, cv, out, rnsq);
    else
      k_conv_mfma<0><<<GCONV, 256, 0, stream>>>(cur, ldc, Wh, bh, cv, nullptr, rnsq);
    k_transp<<<gtr, 256, 0, stream>>>(cv, D_, Vt);
    k_sim_mfma<0><<<GSIM, 256, 0, stream>>>(cv, S);
    k_softmask3<1><<<gsm, 256, 0, stream>>>(S, mask, rnsq, Pb);
    k_att_mfma<<<GATT, 256, 0, stream>>>(Pb, Vt, Rb, h + 1);
    cur = cv;
    ldc = D_;
  }

  // --- pooling ---
  hipMemsetAsync(ps, 0, (size_t)B_ * L_ * 4 * sizeof(float), stream);
  k_pool_mfma<<<GPOOL, 256, 0, stream>>>(Rb, W1t, pool_b1, pool_w2, ps);
  k_weighted2<<<grow, 256, 0, stream>>>(Rb, ps, out + BLD);
}

// Round 5
// 507.241 us; speedup vs baseline: 7.4120x; 1.1534x over previous
//
#include <hip/hip_runtime.h>
#include <math.h>

#define B_ 16
#define L_ 512
#define D_ 768
#define HOPS_ 3
#define LK 64  // shorts per LDS row = 128B = 8 16B slots

typedef __attribute__((ext_vector_type(8))) short s16x8;
typedef __attribute__((ext_vector_type(4))) short s16x4;
typedef __attribute__((ext_vector_type(4))) float f32x4;

typedef __attribute__((address_space(1))) const unsigned gu32;
typedef __attribute__((address_space(3))) unsigned lu32;

// async global->LDS, 16B/lane. LDS dest: wave-uniform base + lane*16 (linear).
__device__ __forceinline__ void gl16(const void* g, void* l) {
  __builtin_amdgcn_global_load_lds((gu32*)g, (lu32*)l, 16, 0, 0);
}

__device__ __forceinline__ short f2bf(float f) {
  unsigned u = __float_as_uint(f);
  unsigned r = (u + 0x7fffu + ((u >> 16) & 1u)) >> 16;
  return (short)r;
}
__device__ __forceinline__ float bf2f(short s) {
  unsigned u = ((unsigned)(unsigned short)s) << 16;
  return __uint_as_float(u);
}
__device__ __forceinline__ float tanh_fast(float x) {
  float e = __expf(2.f * x);  // inf-safe: +inf -> 1, 0 -> -1
  return 1.f - 2.f / (e + 1.f);
}

// READ-side swizzle: phys slot = slot ^ (row&7). LDS is written linearly by
// global_load_lds; the matching inverse permutation is applied to the per-lane
// GLOBAL source address (sw term below). Verified r3/r4: BANK_CONFLICT == 0.
__device__ __forceinline__ s16x8* lds_slot(short (*T)[LK], int row, int slot) {
  return (s16x8*)&T[row][(slot ^ (row & 7)) * 8];
}

// 128x128 tile, 4 waves (2x2 of 64x64), K-step 64
__device__ __forceinline__ void mfma4(short (*As)[LK], short (*Bs)[LK],
                                      f32x4 acc[4][4], int wr, int wc, int lq, int lr) {
#pragma unroll
  for (int ks = 0; ks < 2; ++ks) {
    int sl = ks * 4 + lq;
    s16x8 av[4], bv[4];
#pragma unroll
    for (int m = 0; m < 4; ++m) av[m] = *lds_slot(As, wr * 64 + m * 16 + lr, sl);
#pragma unroll
    for (int n = 0; n < 4; ++n) bv[n] = *lds_slot(Bs, wc * 64 + n * 16 + lr, sl);
#pragma unroll
    for (int m = 0; m < 4; ++m)
#pragma unroll
      for (int n = 0; n < 4; ++n)
        acc[m][n] = __builtin_amdgcn_mfma_f32_16x16x32_bf16(av[m], bv[n], acc[m][n], 0, 0, 0);
  }
}

// 64x128 tile, 4 waves (2x2 of 32x64), K-step 64
__device__ __forceinline__ void mfma2(short (*As)[LK], short (*Bs)[LK],
                                      f32x4 acc[2][4], int wr, int wc, int lq, int lr) {
#pragma unroll
  for (int ks = 0; ks < 2; ++ks) {
    int sl = ks * 4 + lq;
    s16x8 av[2], bv[4];
#pragma unroll
    for (int m = 0; m < 2; ++m) av[m] = *lds_slot(As, wr * 32 + m * 16 + lr, sl);
#pragma unroll
    for (int n = 0; n < 4; ++n) bv[n] = *lds_slot(Bs, wc * 64 + n * 16 + lr, sl);
#pragma unroll
    for (int m = 0; m < 2; ++m)
#pragma unroll
      for (int n = 0; n < 4; ++n)
        acc[m][n] = __builtin_amdgcn_mfma_f32_16x16x32_bf16(av[m], bv[n], acc[m][n], 0, 0, 0);
  }
}

__device__ __forceinline__ int xcd_remap(int bid, int n) {
  return (bid & 7) * (n >> 3) + (bid >> 3);
}

// ---------------------------------------------------------------------------
// sim: S[b][i][j] = sum_k A[i][k]*A[j][k].  SPLIT=1: Xs [L][1536] hi|lo,
// virtual K=2304: A segs {hi,lo,hi}, B segs {hi,hi,lo}. 64x128 tile.
// ---------------------------------------------------------------------------
template <int SPLIT>
__global__ __launch_bounds__(256) void k_sim_mfma(const short* __restrict__ X,
                                                  float* __restrict__ Sout) {
  int wg = xcd_remap(blockIdx.x, gridDim.x);
  int jb = wg & 3, ib = (wg >> 2) & 7, b = wg >> 5;
  int i0 = ib * 64, j0 = jb * 128;
  const int ld = SPLIT ? 1536 : D_;
  const short* Xb = X + (size_t)b * L_ * ld;
  int t = threadIdx.x, lane = t & 63, wid = t >> 6;
  int wr = wid >> 1, wc = wid & 1, lq = lane >> 4, lr = lane & 15;
  __shared__ short As[64][LK];
  __shared__ short Bs[128][LK];
  f32x4 acc[2][4];
#pragma unroll
  for (int m = 0; m < 2; ++m)
#pragma unroll
    for (int n = 0; n < 4; ++n) acc[m][n] = (f32x4){0.f, 0.f, 0.f, 0.f};
  int lrow = lane >> 3;
  int sw = ((lane & 7) ^ lrow) * 8;  // inverse read-swizzle on source
  const short* apg[2];
  short* apl[2];
#pragma unroll
  for (int j = 0; j < 2; ++j) {
    apg[j] = Xb + (size_t)(i0 + wid * 16 + j * 8 + lrow) * ld + sw;
    apl[j] = &As[wid * 16 + j * 8][0];
  }
  const short* bpg[4];
  short* bpl[4];
#pragma unroll
  for (int j = 0; j < 4; ++j) {
    bpg[j] = Xb + (size_t)(j0 + wid * 32 + j * 8 + lrow) * ld + sw;
    bpl[j] = &Bs[wid * 32 + j * 8][0];
  }
  const int K = SPLIT ? 2304 : D_;
  for (int k0 = 0; k0 < K; k0 += LK) {
    int seg = SPLIT ? (k0 / 768) : 0;
    int kl = k0 - seg * 768;
    int ak = kl + ((SPLIT && seg == 1) ? 768 : 0);
    int bk = kl + ((SPLIT && seg == 2) ? 768 : 0);
#pragma unroll
    for (int j = 0; j < 2; ++j) gl16(apg[j] + ak, apl[j]);
#pragma unroll
    for (int j = 0; j < 4; ++j) gl16(bpg[j] + bk, bpl[j]);
    __syncthreads();
    mfma2(As, Bs, acc, wr, wc, lq, lr);
    __syncthreads();
  }
  float* Cb = Sout + (size_t)b * L_ * L_;
#pragma unroll
  for (int m = 0; m < 2; ++m)
#pragma unroll
    for (int n = 0; n < 4; ++n)
#pragma unroll
      for (int rr = 0; rr < 4; ++rr)
        Cb[(size_t)(i0 + wr * 32 + m * 16 + 4 * lq + rr) * L_ +
           (j0 + wc * 64 + n * 16 + lr)] = acc[m][n][rr];
}

// ---------------------------------------------------------------------------
// conv1d(k=3,pad1) im2col GEMM + bias + relu + rowsumsq. 128x128 tile.
// OOB halo rows read from zeroed scratch via per-lane pointer redirect.
// ---------------------------------------------------------------------------
template <int WF32>
__global__ __launch_bounds__(256) void k_conv_mfma(const short* __restrict__ X, int ldx,
                                                   const short* __restrict__ Wt2,
                                                   const float* __restrict__ bias,
                                                   short* __restrict__ Ybf,
                                                   float* __restrict__ Yf,
                                                   float* __restrict__ rnsq,
                                                   const short* __restrict__ zbuf) {
  int wg = xcd_remap(blockIdx.x, gridDim.x);
  int ob = wg % 6;
  int m_ = wg / 6;
  int b = m_ >> 2, l0 = (m_ & 3) * 128, o0 = ob * 128;
  const short* Xb = X + (size_t)b * L_ * ldx;
  int t = threadIdx.x, lane = t & 63, wid = t >> 6;
  int wr = wid >> 1, wc = wid & 1, lq = lane >> 4, lr = lane & 15;
  __shared__ short As[128][LK];
  __shared__ short Bs[128][LK];
  f32x4 acc[4][4];
#pragma unroll
  for (int m = 0; m < 4; ++m)
#pragma unroll
    for (int n = 0; n < 4; ++n) acc[m][n] = (f32x4){0.f, 0.f, 0.f, 0.f};
  int lrow = lane >> 3;
  int sw = ((lane & 7) ^ lrow) * 8;
  int arow[4];
  const short* bpg[4];
  short* apl[4];
  short* bpl[4];
#pragma unroll
  for (int j = 0; j < 4; ++j) {
    arow[j] = wid * 32 + j * 8 + lrow;
    apl[j] = &As[wid * 32 + j * 8][0];
    bpg[j] = Wt2 + (size_t)(o0 + wid * 32 + j * 8 + lrow) * (3 * D_) + sw;
    bpl[j] = &Bs[wid * 32 + j * 8][0];
  }
  const short* zp = zbuf + sw;
  for (int k0 = 0; k0 < 3 * D_; k0 += LK) {
    int tap = k0 / D_;
    int kl = k0 - tap * D_;
#pragma unroll
    for (int j = 0; j < 4; ++j) {
      int l = l0 + arow[j] + tap - 1;
      const short* src =
          ((unsigned)l < (unsigned)L_) ? Xb + (size_t)l * ldx + kl + sw : zp;
      gl16(src, apl[j]);
    }
#pragma unroll
    for (int j = 0; j < 4; ++j) gl16(bpg[j] + k0, bpl[j]);
    __syncthreads();
    mfma4(As, Bs, acc, wr, wc, lq, lr);
    __syncthreads();
  }
  float bv[4];
#pragma unroll
  for (int n = 0; n < 4; ++n) bv[n] = bias[o0 + wc * 64 + n * 16 + lr];
#pragma unroll
  for (int m = 0; m < 4; ++m)
#pragma unroll
    for (int rr = 0; rr < 4; ++rr) {
      int l = l0 + wr * 64 + m * 16 + 4 * lq + rr;
      size_t rowoff = ((size_t)b * L_ + l) * D_;
      float ss = 0.f;
#pragma unroll
      for (int n = 0; n < 4; ++n) {
        int o = o0 + wc * 64 + n * 16 + lr;
        float v = fmaxf(acc[m][n][rr] + bv[n], 0.f);
        Ybf[rowoff + o] = f2bf(v);
        if (WF32) Yf[rowoff + o] = v;
        ss += v * v;
      }
      ss += __shfl_xor(ss, 1);
      ss += __shfl_xor(ss, 2);
      ss += __shfl_xor(ss, 4);
      ss += __shfl_xor(ss, 8);
      if (lr == 0) atomicAdd(&rnsq[(size_t)b * L_ + l], ss);
    }
}

// ---------------------------------------------------------------------------
// att apply: R[b][i][hop][:] = P[b][i][:]*V; P bf16 [L][L], Vt bf16 [D][L].
// ---------------------------------------------------------------------------
__global__ __launch_bounds__(256) void k_att_mfma(const short* __restrict__ P,
                                                  const short* __restrict__ Vt,
                                                  short* __restrict__ Rb, int hop) {
  int wg = xcd_remap(blockIdx.x, gridDim.x);
  int db = wg % 6;
  int r2 = wg / 6;
  int b = r2 >> 2, i0 = (r2 & 3) * 128, d0 = db * 128;
  const short* Pb = P + (size_t)b * L_ * L_;
  const short* Vb = Vt + (size_t)b * D_ * L_;
  int t = threadIdx.x, lane = t & 63, wid = t >> 6;
  int wr = wid >> 1, wc = wid & 1, lq = lane >> 4, lr = lane & 15;
  __shared__ short As[128][LK];
  __shared__ short Bs[128][LK];
  f32x4 acc[4][4];
#pragma unroll
  for (int m = 0; m < 4; ++m)
#pragma unroll
    for (int n = 0; n < 4; ++n) acc[m][n] = (f32x4){0.f, 0.f, 0.f, 0.f};
  int lrow = lane >> 3;
  int sw = ((lane & 7) ^ lrow) * 8;
  const short* apg[4];
  const short* bpg[4];
  short* apl[4];
  short* bpl[4];
#pragma unroll
  for (int j = 0; j < 4; ++j) {
    apg[j] = Pb + (size_t)(i0 + wid * 32 + j * 8 + lrow) * L_ + sw;
    apl[j] = &As[wid * 32 + j * 8][0];
    bpg[j] = Vb + (size_t)(d0 + wid * 32 + j * 8 + lrow) * L_ + sw;
    bpl[j] = &Bs[wid * 32 + j * 8][0];
  }
  for (int k0 = 0; k0 < L_; k0 += LK) {
#pragma unroll
    for (int j = 0; j < 4; ++j) gl16(apg[j] + k0, apl[j]);
#pragma unroll
    for (int j = 0; j < 4; ++j) gl16(bpg[j] + k0, bpl[j]);
    __syncthreads();
    mfma4(As, Bs, acc, wr, wc, lq, lr);
    __syncthreads();
  }
#pragma unroll
  for (int m = 0; m < 4; ++m)
#pragma unroll
    for (int n = 0; n < 4; ++n)
#pragma unroll
      for (int rr = 0; rr < 4; ++rr) {
        int i = i0 + wr * 64 + m * 16 + 4 * lq + rr;
        int d = d0 + wc * 64 + n * 16 + lr;
        Rb[((size_t)(b * L_ + i) * 4 + hop) * D_ + d] = f2bf(acc[m][n][rr]);
      }
}

// ---------------------------------------------------------------------------
// pool GEMM + fast-tanh·w2 epilogue. 128x128 tile. Rb [32768][768] bf16.
// ---------------------------------------------------------------------------
__global__ __launch_bounds__(256) void k_pool_mfma(const short* __restrict__ Rb,
                                                   const short* __restrict__ W1t,
                                                   const float* __restrict__ b1,
                                                   const float* __restrict__ w2,
                                                   float* __restrict__ ps) {
  int wg = xcd_remap(blockIdx.x, gridDim.x);
  int eb = wg % 6;
  int r0 = (wg / 6) * 128, e0 = eb * 128;
  int t = threadIdx.x, lane = t & 63, wid = t >> 6;
  int wr = wid >> 1, wc = wid & 1, lq = lane >> 4, lr = lane & 15;
  __shared__ short As[128][LK];
  __shared__ short Bs[128][LK];
  f32x4 acc[4][4];
#pragma unroll
  for (int m = 0; m < 4; ++m)
#pragma unroll
    for (int n = 0; n < 4; ++n) acc[m][n] = (f32x4){0.f, 0.f, 0.f, 0.f};
  int lrow = lane >> 3;
  int sw = ((lane & 7) ^ lrow) * 8;
  const short* apg[4];
  const short* bpg[4];
  short* apl[4];
  short* bpl[4];
#pragma unroll
  for (int j = 0; j < 4; ++j) {
    apg[j] = Rb + (size_t)(r0 + wid * 32 + j * 8 + lrow) * D_ + sw;
    apl[j] = &As[wid * 32 + j * 8][0];
    bpg[j] = W1t + (size_t)(e0 + wid * 32 + j * 8 + lrow) * D_ + sw;
    bpl[j] = &Bs[wid * 32 + j * 8][0];
  }
  for (int k0 = 0; k0 < D_; k0 += LK) {
#pragma unroll
    for (int j = 0; j < 4; ++j) gl16(apg[j] + k0, apl[j]);
#pragma unroll
    for (int j = 0; j < 4; ++j) gl16(bpg[j] + k0, bpl[j]);
    __syncthreads();
    mfma4(As, Bs, acc, wr, wc, lq, lr);
    __syncthreads();
  }
  float b1v[4], w2v[4];
#pragma unroll
  for (int n = 0; n < 4; ++n) {
    int e = e0 + wc * 64 + n * 16 + lr;
    b1v[n] = b1[e];
    w2v[n] = w2[e];
  }
#pragma unroll
  for (int m = 0; m < 4; ++m)
#pragma unroll
    for (int rr = 0; rr < 4; ++rr) {
      float p = 0.f;
#pragma unroll
      for (int n = 0; n < 4; ++n) p += tanh_fast(acc[m][n][rr] + b1v[n]) * w2v[n];
      p += __shfl_xor(p, 1);
      p += __shfl_xor(p, 2);
      p += __shfl_xor(p, 4);
      p += __shfl_xor(p, 8);
      if (lr == 0) atomicAdd(&ps[r0 + wr * 64 + m * 16 + 4 * lq + rr], p);
    }
}

// ---------------------------------------------------------------------------
// bf16 transpose: in [L][ld] -> outT [D][L] (per batch)
// ---------------------------------------------------------------------------
__global__ __launch_bounds__(256) void k_transp(const short* __restrict__ in, int ld,
                                                short* __restrict__ outT) {
  int l0 = blockIdx.x * 32, d0 = blockIdx.y * 32, b = blockIdx.z;
  __shared__ short tile[32][34];
  int r = threadIdx.x >> 5, c = threadIdx.x & 31;
  const short* ib = in + (size_t)b * L_ * ld;
#pragma unroll
  for (int i = 0; i < 4; ++i)
    tile[r + 8 * i][c] = ib[(size_t)(l0 + r + 8 * i) * ld + d0 + c];
  __syncthreads();
  short* ob = outT + (size_t)b * D_ * L_;
#pragma unroll
  for (int i = 0; i < 4; ++i)
    ob[(size_t)(d0 + r + 8 * i) * L_ + l0 + c] = tile[c][r + 8 * i];
}

// ---------------------------------------------------------------------------
// softmask: one wave per row. S f32 -> P bf16.
// ---------------------------------------------------------------------------
template <int NORM>
__global__ __launch_bounds__(256) void k_softmask3(const float* __restrict__ S,
                                                   const float* __restrict__ mask,
                                                   const float* __restrict__ rsq,
                                                   short* __restrict__ P) {
  int b = blockIdx.y;
  int i = blockIdx.x * 4 + (threadIdx.x >> 6);
  int l = threadIdx.x & 63;
  const float* row = S + ((size_t)b * L_ + i) * L_;
  const float* mb = mask + (size_t)b * L_;
  float v[8], mk[8];
  {
    float4 s0 = ((const float4*)row)[l * 2];
    float4 s1 = ((const float4*)row)[l * 2 + 1];
    float4 m0 = ((const float4*)mb)[l * 2];
    float4 m1 = ((const float4*)mb)[l * 2 + 1];
    v[0] = s0.x; v[1] = s0.y; v[2] = s0.z; v[3] = s0.w;
    v[4] = s1.x; v[5] = s1.y; v[6] = s1.z; v[7] = s1.w;
    mk[0] = m0.x; mk[1] = m0.y; mk[2] = m0.z; mk[3] = m0.w;
    mk[4] = m1.x; mk[5] = m1.y; mk[6] = m1.z; mk[7] = m1.w;
  }
  if (NORM) {
    float ri = 1.f / fmaxf(sqrtf(rsq[(size_t)b * L_ + i]), 1e-12f);
    const float4* rq = (const float4*)(rsq + (size_t)b * L_);
    float4 q0 = rq[l * 2], q1 = rq[l * 2 + 1];
    float qq[8] = {q0.x, q0.y, q0.z, q0.w, q1.x, q1.y, q1.z, q1.w};
#pragma unroll
    for (int e = 0; e < 8; ++e) v[e] *= ri / fmaxf(sqrtf(qq[e]), 1e-12f);
  }
  float m = v[0];
#pragma unroll
  for (int e = 1; e < 8; ++e) m = fmaxf(m, v[e]);
#pragma unroll
  for (int s = 1; s < 64; s <<= 1) m = fmaxf(m, __shfl_xor(m, s));
  float y[8], sum = 0.f;
#pragma unroll
  for (int e = 0; e < 8; ++e) {
    y[e] = __expf(v[e] - m) * mk[e];
    sum += y[e];
  }
#pragma unroll
  for (int s = 1; s < 64; s <<= 1) sum += __shfl_xor(sum, s);
  float inv = mb[i] / (sum + 1e-10f);
  s16x8 pk;
#pragma unroll
  for (int e = 0; e < 8; ++e) pk[e] = f2bf(y[e] * inv);
  ((s16x8*)(P + ((size_t)b * L_ + i) * L_))[l] = pk;
}

// inputs f32 -> Xs bf16 [B*L][1536] = [hi | lo]
__global__ void k_prep4(const float* __restrict__ in, short* __restrict__ Xs) {
  size_t idx = (size_t)blockIdx.x * 256 + threadIdx.x;
  if (idx >= (size_t)B_ * L_ * D_ / 4) return;
  float4 x = ((const float4*)in)[idx];
  size_t base = idx * 4;
  size_t bl = base / D_;
  int d = (int)(base % D_);
  float xs[4] = {x.x, x.y, x.z, x.w};
  s16x4 hi, lo;
#pragma unroll
  for (int e = 0; e < 4; ++e) {
    hi[e] = f2bf(xs[e]);
    lo[e] = f2bf(xs[e] - bf2f(hi[e]));
  }
  *(s16x4*)&Xs[bl * 1536 + d] = hi;
  *(s16x4*)&Xs[bl * 1536 + 768 + d] = lo;
}

// conv_w [h][o][i][kk] -> Wt2 bf16 [h][o][kk*768+i]
__global__ void k_wtrans2(const float* __restrict__ w, short* __restrict__ Wt2) {
  size_t idx = (size_t)blockIdx.x * 256 + threadIdx.x;
  const size_t total = (size_t)HOPS_ * D_ * 3 * D_;
  if (idx >= total) return;
  int i = (int)(idx % D_);
  size_t tmp = idx / D_;
  int kk = (int)(tmp % 3);
  tmp /= 3;
  int o = (int)(tmp % D_);
  int h = (int)(tmp / D_);
  Wt2[idx] = f2bf(w[(((size_t)h * D_ + o) * D_ + i) * 3 + kk]);
}

// W1 [d][e] -> W1t bf16 [e][d]
__global__ void k_w1t(const float* __restrict__ W1, short* __restrict__ W1t) {
  size_t idx = (size_t)blockIdx.x * 256 + threadIdx.x;
  if (idx >= (size_t)D_ * D_) return;
  int e = (int)(idx / D_), d = (int)(idx % D_);
  W1t[idx] = f2bf(W1[(size_t)d * D_ + e]);
}

// out[b][l][d] = sum_h softmax(ps)[h] * Rb[bl][h][d]
__global__ __launch_bounds__(256) void k_weighted2(const short* __restrict__ Rb,
                                                   const float* __restrict__ ps,
                                                   float* __restrict__ out) {
  int b = blockIdx.y, l = blockIdx.x;
  size_t bl = (size_t)b * L_ + l;
  const float* p = ps + bl * 4;
  float s0 = p[0], s1 = p[1], s2 = p[2], s3 = p[3];
  float m = fmaxf(fmaxf(s0, s1), fmaxf(s2, s3));
  float e0 = __expf(s0 - m), e1 = __expf(s1 - m), e2 = __expf(s2 - m),
        e3 = __expf(s3 - m);
  float inv = 1.f / (e0 + e1 + e2 + e3);
  e0 *= inv; e1 *= inv; e2 *= inv; e3 *= inv;
  const short* Rrow = Rb + bl * 4 * D_;
  float* orow = out + bl * D_;
  for (int d = threadIdx.x; d < D_; d += 256) {
    orow[d] = e0 * bf2f(Rrow[d]) + e1 * bf2f(Rrow[D_ + d]) +
              e2 * bf2f(Rrow[2 * D_ + d]) + e3 * bf2f(Rrow[3 * D_ + d]);
  }
}

extern "C" void kernel_launch(void* const* d_in, const int* in_sizes, int n_in,
                              void* d_out, int out_size, void* d_ws, size_t ws_size,
                              hipStream_t stream) {
  const float* inputs  = (const float*)d_in[0];
  const float* mask    = (const float*)d_in[1];
  const float* conv_w  = (const float*)d_in[2];
  const float* conv_b  = (const float*)d_in[3];
  const float* pool_w1 = (const float*)d_in[4];
  const float* pool_b1 = (const float*)d_in[5];
  const float* pool_w2 = (const float*)d_in[6];
  float* out = (float*)d_out;

  const size_t BLD = (size_t)B_ * L_ * D_;
  const size_t BLL = (size_t)B_ * L_ * L_;

  char* w = (char*)d_ws;
  short* Xs   = (short*)w; w += (size_t)2 * BLD * 2;               // 25.2 MB [hi|lo]
  short* Wt2  = (short*)w; w += (size_t)HOPS_ * 3 * D_ * D_ * 2;   // 10.6 MB
  short* W1t  = (short*)w; w += (size_t)D_ * D_ * 2;               // 1.2 MB
  float* S    = (float*)w; w += BLL * 4;                           // 16.8 MB
  short* Pb   = (short*)w; w += BLL * 2;                           // 8.4 MB
  short* YbfA = (short*)w; w += BLD * 2;                           // 12.6 MB
  short* YbfB = (short*)w; w += BLD * 2;                           // 12.6 MB
  short* Vt   = (short*)w; w += BLD * 2;                           // 12.6 MB
  short* Rb   = (short*)w; w += 4 * BLD * 2;                       // 50.3 MB
  float* rnsq = (float*)w; w += (size_t)B_ * L_ * 4;
  float* ps   = (float*)w; w += (size_t)B_ * L_ * 4 * 4;
  short* zbuf = (short*)w; w += 1024;                              // zero halo page

  // --- prep ---
  hipMemsetAsync(zbuf, 0, 1024, stream);
  k_prep4<<<dim3((unsigned)((BLD / 4 + 255) / 256)), 256, 0, stream>>>(inputs, Xs);
  {
    size_t tot = (size_t)HOPS_ * D_ * 3 * D_;
    k_wtrans2<<<dim3((unsigned)((tot + 255) / 256)), 256, 0, stream>>>(conv_w, Wt2);
  }
  k_w1t<<<dim3((unsigned)(((size_t)D_ * D_ + 255) / 256)), 256, 0, stream>>>(pool_w1, W1t);

  dim3 gtr(L_ / 32, D_ / 32, B_);
  dim3 gsm(L_ / 4, B_);
  dim3 grow(L_, B_);
  const int GSIM = (L_ / 64) * (L_ / 128) * B_;        // 512
  const int GCONV = (D_ / 128) * (L_ / 128) * B_;      // 384
  const int GATT = GCONV;                              // 384
  const int GPOOL = (D_ / 128) * (4 * B_ * L_ / 128);  // 1536

  // --- hop 0: split-bf16 similarity on raw inputs ---
  k_transp<<<gtr, 256, 0, stream>>>(Xs, 1536, Vt);
  k_sim_mfma<1><<<GSIM, 256, 0, stream>>>(Xs, S);
  k_softmask3<0><<<gsm, 256, 0, stream>>>(S, mask, nullptr, Pb);
  k_att_mfma<<<GATT, 256, 0, stream>>>(Pb, Vt, Rb, 0);

  // --- hops 1..3 ---
  const short* cur = Xs;
  int ldc = 1536;
  for (int h = 0; h < HOPS_; ++h) {
    short* cv = (h & 1) ? YbfB : YbfA;
    const short* Wh = Wt2 + (size_t)h * 3 * D_ * D_;
    const float* bh = conv_b + (size_t)h * D_;
    hipMemsetAsync(rnsq, 0, (size_t)B_ * L_ * sizeof(float), stream);
    if (h == HOPS_ - 1)
      k_conv_mfma<1><<<GCONV, 256, 0, stream>>>(cur, ldc, Wh, bh, cv, out, rnsq, zbuf);
    else
      k_conv_mfma<0><<<GCONV, 256, 0, stream>>>(cur, ldc, Wh, bh, cv, nullptr, rnsq, zbuf);
    k_transp<<<gtr, 256, 0, stream>>>(cv, D_, Vt);
    k_sim_mfma<0><<<GSIM, 256, 0, stream>>>(cv, S);
    k_softmask3<1><<<gsm, 256, 0, stream>>>(S, mask, rnsq, Pb);
    k_att_mfma<<<GATT, 256, 0, stream>>>(Pb, Vt, Rb, h + 1);
    cur = cv;
    ldc = D_;
  }

  // --- pooling ---
  hipMemsetAsync(ps, 0, (size_t)B_ * L_ * 4 * sizeof(float), stream);
  k_pool_mfma<<<GPOOL, 256, 0, stream>>>(Rb, W1t, pool_b1, pool_w2, ps);
  k_weighted2<<<grow, 256, 0, stream>>>(Rb, ps, out + BLD);
}